// Round 1
// baseline (605.452 us; speedup 1.0000x reference)
//
#include <hip/hip_runtime.h>
#include <stdint.h>

typedef unsigned short ushort_t;
typedef __attribute__((ext_vector_type(8))) short bf16x8;
typedef __attribute__((ext_vector_type(4))) float f32x4;
typedef __attribute__((ext_vector_type(4))) unsigned short u16x4;

#define B_ 2
#define T_ 2048
#define D_ 2048
#define H_ 16
#define HD_ 128
#define BT_ 4096

__device__ __forceinline__ ushort_t f2bf(float f) {
  unsigned u = __float_as_uint(f);
  u += 0x7FFFu + ((u >> 16) & 1u);   // RNE
  return (ushort_t)(u >> 16);
}

__device__ __forceinline__ void async16(const void* g, void* l) {
  __builtin_amdgcn_global_load_lds(
      (const __attribute__((address_space(1))) unsigned int*)g,
      (__attribute__((address_space(3))) unsigned int*)l, 16, 0, 0);
}

// ---------------- elementwise cast x -> bf16 ----------------
__global__ void k_cast_x(const float* __restrict__ in, ushort_t* __restrict__ out) {
  int i = blockIdx.x * 256 + threadIdx.x;          // 4 elements per thread
  float4 v = ((const float4*)in)[i];
  u16x4 r = { f2bf(v.x), f2bf(v.y), f2bf(v.z), f2bf(v.w) };
  ((u16x4*)out)[i] = r;
}

// ---------------- weight transpose+cast: w[K][N] f32 -> wt[N][K] bf16 ----------------
__global__ void k_twT(const float* __restrict__ w, ushort_t* __restrict__ wt) {
  __shared__ float tile[32][33];
  int tx = threadIdx.x, ty = threadIdx.y;
  int x = blockIdx.x * 32 + tx;        // N index
  int y0 = blockIdx.y * 32;            // K index
#pragma unroll
  for (int k = 0; k < 4; ++k)
    tile[ty + k * 8][tx] = w[(size_t)(y0 + ty + k * 8) * D_ + x];
  __syncthreads();
  int ox = blockIdx.y * 32 + tx;       // K contiguous on write
  int oy0 = blockIdx.x * 32;           // N
#pragma unroll
  for (int k = 0; k < 4; ++k)
    wt[(size_t)(oy0 + ty + k * 8) * D_ + ox] = f2bf(tile[tx][ty + k * 8]);
}

// ---------------- GEMM: C[M=4096][N=2048] = A(bf16 MxK) * Bt(bf16 NxK)^T + bias ----------------
// 2-phase double-buffered K-loop (T3 minimum recipe): prefetch buf^1 overlaps
// ds_read+MFMA on buf; ONE counted vmcnt(0)+s_barrier per K-step (was 2 full drains).
// XCD-bijective block swizzle (512%8==0) keeps A-panels XCD-local.
// EPI 0: store fp32.  1: store bf16.  2: store fp32 + bf16.  3: gate (out = aux * sigmoid(val))
template <int EPI>
__global__ __launch_bounds__(256) void k_gemm(
    const ushort_t* __restrict__ A, const ushort_t* __restrict__ Bt,
    const float* __restrict__ bias, float* __restrict__ outF,
    ushort_t* __restrict__ outB, const float* __restrict__ aux) {
  __shared__ __align__(16) short As[2][128 * 32];
  __shared__ __align__(16) short Bs[2][128 * 32];
  const int tid = threadIdx.x;
  const int wid = tid >> 6, lane = tid & 63;
  const int l15 = lane & 15, kq = lane >> 4;
  const int m0 = (wid >> 1) * 64, n0 = (wid & 1) * 64;
  const int flat = blockIdx.y * gridDim.x + blockIdx.x;   // 512 blocks
  const int swz = (flat & 7) * 64 + (flat >> 3);          // bijective XCD chunking
  const int tileM = (swz >> 4) * 128, tileN = (swz & 15) * 128;

  f32x4 acc[4][4];
#pragma unroll
  for (int i = 0; i < 4; ++i)
#pragma unroll
    for (int j = 0; j < 4; ++j) acc[i][j] = (f32x4){0.f, 0.f, 0.f, 0.f};

  auto stage = [&](int sbuf, int k0) {
#pragma unroll
    for (int rr = 0; rr < 2; ++rr) {
      int chunk = rr * 256 + tid;
      int row = chunk >> 2, p = chunk & 3;
      int gc = p ^ ((row >> 1) & 3);   // XOR-swizzled global chunk (bank-conflict fix)
      async16(A + (size_t)(tileM + row) * D_ + k0 + gc * 8,
              &As[sbuf][(rr * 256 + wid * 64) * 8]);
      async16(Bt + (size_t)(tileN + row) * D_ + k0 + gc * 8,
              &Bs[sbuf][(rr * 256 + wid * 64) * 8]);
    }
  };

  stage(0, 0);
  __asm__ volatile("s_waitcnt vmcnt(0)" ::: "memory");
  __builtin_amdgcn_s_barrier();

  int buf = 0;
  for (int k0 = 0; k0 < D_; k0 += 32) {
    if (k0 + 32 < D_) stage(buf ^ 1, k0 + 32);   // prefetch overlaps compute below
    bf16x8 a[4], b[4];
#pragma unroll
    for (int i = 0; i < 4; ++i) {
      int row = m0 + i * 16 + l15;
      a[i] = *(const bf16x8*)&As[buf][row * 32 + (kq ^ ((row >> 1) & 3)) * 8];
    }
#pragma unroll
    for (int j = 0; j < 4; ++j) {
      int row = n0 + j * 16 + l15;
      b[j] = *(const bf16x8*)&Bs[buf][row * 32 + (kq ^ ((row >> 1) & 3)) * 8];
    }
#pragma unroll
    for (int i = 0; i < 4; ++i)
#pragma unroll
      for (int j = 0; j < 4; ++j)
        acc[i][j] = __builtin_amdgcn_mfma_f32_16x16x32_bf16(a[i], b[j], acc[i][j], 0, 0, 0);
    __asm__ volatile("s_waitcnt vmcnt(0)" ::: "memory");  // prefetch landed
    __builtin_amdgcn_s_barrier();
    buf ^= 1;
  }

#pragma unroll
  for (int i = 0; i < 4; ++i) {
#pragma unroll
    for (int j = 0; j < 4; ++j) {
#pragma unroll
      for (int r = 0; r < 4; ++r) {
        int gm = tileM + m0 + i * 16 + kq * 4 + r;   // C/D: row = quad*4 + reg
        int gn = tileN + n0 + j * 16 + l15;          //      col = lane&15
        size_t idx = (size_t)gm * D_ + gn;
        float val = acc[i][j][r] + bias[gn];
        if (EPI == 0) {
          outF[idx] = val;
        } else if (EPI == 1) {
          outB[idx] = f2bf(val);
        } else if (EPI == 2) {
          outF[idx] = val; outB[idx] = f2bf(val);
        } else {
          float sg = 1.f / (1.f + __expf(-val));
          outF[idx] = aux[idx] * sg;
        }
      }
    }
  }
}

// ---------------- fused RMSNorm (full D) + RoPE, fp32 in -> bf16 out (x oscale) ----------------
__global__ void k_normrope(const float* __restrict__ in, const float* __restrict__ g,
                           const float* __restrict__ cs, const float* __restrict__ sn,
                           ushort_t* __restrict__ out, float oscale) {
  const int row = blockIdx.x;            // 0..4095 = b*T + t
  const int t = row & (T_ - 1);
  const float* x = in + (size_t)row * D_;
  const int tid = threadIdx.x;
  float ss = 0.f;
#pragma unroll
  for (int i = tid; i < 512; i += 256) {
    float4 v = ((const float4*)x)[i];
    ss += v.x * v.x + v.y * v.y + v.z * v.z + v.w * v.w;
  }
#pragma unroll
  for (int off = 1; off < 64; off <<= 1) ss += __shfl_xor(ss, off, 64);
  __shared__ float part[4];
  if ((tid & 63) == 0) part[tid >> 6] = ss;
  __syncthreads();
  float rstd = rsqrtf((part[0] + part[1] + part[2] + part[3]) * (1.f / (float)D_) + 1e-6f);
  rstd *= oscale;                        // fold attention scale*log2e into Q
#pragma unroll
  for (int p = tid; p < 1024; p += 256) {
    int head = p >> 6, i = p & 63;
    int e1 = head * HD_ + i, e2 = e1 + 64;
    float x1 = x[e1] * rstd * g[e1];
    float x2 = x[e2] * rstd * g[e2];
    float c = cs[t * 64 + i], s = sn[t * 64 + i];
    out[(size_t)row * D_ + e1] = f2bf(x1 * c - s * x2);
    out[(size_t)row * D_ + e2] = f2bf(x2 * c + s * x1);
  }
}

// ---------------- V transpose per head: v[b][t][h*128+d] -> vt[bh][d][t] ----------------
__global__ void k_tv(const ushort_t* __restrict__ v, ushort_t* __restrict__ vt) {
  __shared__ ushort_t tile[32][33];
  int bh = blockIdx.z, b = bh >> 4, h = bh & 15;
  int tx = threadIdx.x, ty = threadIdx.y;
  int d = blockIdx.x * 32 + tx;
  int t0 = blockIdx.y * 32;
#pragma unroll
  for (int k = 0; k < 4; ++k)
    tile[ty + k * 8][tx] = v[(size_t)(b * T_ + t0 + ty + k * 8) * D_ + h * HD_ + d];
  __syncthreads();
  int ot = t0 + tx;
  int od0 = blockIdx.x * 32;
#pragma unroll
  for (int k = 0; k < 4; ++k)
    vt[((size_t)bh * HD_ + od0 + ty + k * 8) * T_ + ot] = tile[tx][ty + k * 8];
}

// ---------------- flash v4: 128 q/block, fixed-max softmax (||q||=||k||=sqrt(128)
// exactly by RMSNorm -> |score|<=11.32, fp32-safe without running max), K double-buf,
// V single-buf, swizzled P.
// COUNTED vmcnt (T4): V staged first, K(kt+1) second; [B] waits vmcnt(4) so the K
// prefetch stays in flight across the mid-iteration barrier (was drained to 0 by
// __syncthreads, nullifying the double buffer). Per-wave wait BEFORE each raw
// s_barrier keeps cross-wave staging safe. setprio(1) around MFMA clusters (T5).
// XCD swizzle (T1): each XCD owns 4 contiguous bh -> K+V working set = 4MB = one L2.
__global__ __launch_bounds__(256) void k_flash(
    const ushort_t* __restrict__ Q, const ushort_t* __restrict__ K,
    const ushort_t* __restrict__ Vt, ushort_t* __restrict__ O) {
  __shared__ __align__(16) short Ks[2][64 * 128];   // [buf][key][d]
  __shared__ __align__(16) short Vs[128 * 64];      // [d][key]
  __shared__ __align__(16) short Ps[4][32 * 64];    // per-wave P, XOR-swizzled chunks

  const int tid = threadIdx.x;
  const int wid = tid >> 6, lane = tid & 63;
  const int l15 = lane & 15, kq = lane >> 4;
  const int flat = blockIdx.y * gridDim.x + blockIdx.x;   // 512 blocks
  const int swz = (flat & 7) * 64 + (flat >> 3);          // bijective XCD chunking
  const int bh = swz >> 4, b = bh >> 4, h = bh & 15;
  const int q0 = (swz & 15) * 128;

  const ushort_t* kp[4];
  const ushort_t* vp[4];
#pragma unroll
  for (int rr = 0; rr < 4; ++rr) {
    int c = rr * 256 + tid;
    int krow = c >> 4, kc = (c & 15) ^ (krow & 15);
    kp[rr] = K + (size_t)(b * T_ + krow) * D_ + h * HD_ + kc * 8;
    int drow = c >> 3, vc = (c & 7) ^ (drow & 7);
    vp[rr] = Vt + ((size_t)bh * HD_ + drow) * T_ + vc * 8;
  }

  // Q A-frags, two 16-row halves (rows q0 + wid*32 + {0,16} + l15); scale pre-folded
  bf16x8 qa0[4], qa1[4];
  {
    const ushort_t* qp0 = Q + (size_t)(b * T_ + q0 + wid * 32 + l15) * D_ + h * HD_ + kq * 8;
    const ushort_t* qp1 = qp0 + 16 * D_;
#pragma unroll
    for (int kk = 0; kk < 4; ++kk) {
      qa0[kk] = *(const bf16x8*)(qp0 + kk * 32);
      qa1[kk] = *(const bf16x8*)(qp1 + kk * 32);
    }
  }

  f32x4 o0[8], o1[8];
#pragma unroll
  for (int dt = 0; dt < 8; ++dt) {
    o0[dt] = (f32x4){0.f, 0.f, 0.f, 0.f};
    o1[dt] = (f32x4){0.f, 0.f, 0.f, 0.f};
  }
  float l0[4] = {0.f, 0.f, 0.f, 0.f}, l1[4] = {0.f, 0.f, 0.f, 0.f};

  // prologue: stage K tile 0 into buf 0
#pragma unroll
  for (int rr = 0; rr < 4; ++rr)
    async16(kp[rr], &Ks[0][(rr * 256 + wid * 64) * 8]);

  for (int kt = 0; kt < 32; ++kt) {
    const int buf = kt & 1;
    // [A] my K(kt) loads done -> barrier -> all waves' K(kt) staged;
    // also fences V writes below vs prior PV reads (consumed pre-barrier via lgkm)
    __asm__ volatile("s_waitcnt vmcnt(0)" ::: "memory");
    __builtin_amdgcn_s_barrier();

    // issue V(kt) FIRST (needed at [B]), then K(kt+1) (needed at next [A]) —
    // issue order makes vmcnt(4) at [B] mean "V done, K still in flight"
#pragma unroll
    for (int rr = 0; rr < 4; ++rr)
      async16(vp[rr] + (size_t)kt * 64, &Vs[(rr * 256 + wid * 64) * 8]);
    if (kt + 1 < 32) {
#pragma unroll
      for (int rr = 0; rr < 4; ++rr)
        async16(kp[rr] + (size_t)(kt + 1) * 64 * D_, &Ks[buf ^ 1][(rr * 256 + wid * 64) * 8]);
    }

    // S = Q*K^T for both halves, sharing kf reads
    f32x4 s0[4], s1[4];
#pragma unroll
    for (int j = 0; j < 4; ++j) { s0[j] = (f32x4){0.f,0.f,0.f,0.f}; s1[j] = (f32x4){0.f,0.f,0.f,0.f}; }
    __builtin_amdgcn_s_setprio(1);
#pragma unroll
    for (int j = 0; j < 4; ++j) {
#pragma unroll
      for (int kk = 0; kk < 4; ++kk) {
        int row = j * 16 + l15;
        bf16x8 kf = *(const bf16x8*)&Ks[buf][row * 128 + ((kk * 4 + kq) ^ l15) * 8];
        s0[j] = __builtin_amdgcn_mfma_f32_16x16x32_bf16(qa0[kk], kf, s0[j], 0, 0, 0);
        s1[j] = __builtin_amdgcn_mfma_f32_16x16x32_bf16(qa1[kk], kf, s1[j], 0, 0, 0);
      }
    }
    __builtin_amdgcn_s_setprio(0);

    // fixed-max softmax (exp2 domain), per-lane partial sums, swizzled P store
#pragma unroll
    for (int r = 0; r < 4; ++r) {
      const int row0 = kq * 4 + r, row1 = row0 + 16;
      const int sw0 = (row0 & 7) ^ ((row0 & 8) >> 2);
      const int sw1 = (row1 & 7) ^ ((row1 & 8) >> 2);
#pragma unroll
      for (int j = 0; j < 4; ++j) {
        float p0 = __builtin_amdgcn_exp2f(s0[j][r]); l0[r] += p0;
        float p1 = __builtin_amdgcn_exp2f(s1[j][r]); l1[r] += p1;
        int c = j * 2 + (l15 >> 3);
        Ps[wid][row0 * 64 + (c ^ sw0) * 8 + (l15 & 7)] = (short)f2bf(p0);
        Ps[wid][row1 * 64 + (c ^ sw1) * 8 + (l15 & 7)] = (short)f2bf(p1);
      }
    }
    __asm__ volatile("s_waitcnt lgkmcnt(0)" ::: "memory");   // P writes -> cross-lane reads

    bf16x8 pf0[2], pf1[2];
#pragma unroll
    for (int kk2 = 0; kk2 < 2; ++kk2) {
      int r0 = l15, r1 = 16 + l15;
      int c0 = (kk2 * 4 + kq) ^ (r0 & 7) ^ ((r0 & 8) >> 2);
      int c1 = (kk2 * 4 + kq) ^ (r1 & 7) ^ ((r1 & 8) >> 2);
      pf0[kk2] = *(const bf16x8*)&Ps[wid][r0 * 64 + c0 * 8];
      pf1[kk2] = *(const bf16x8*)&Ps[wid][r1 * 64 + c1 * 8];
    }

    // [B] my V(kt) (oldest 4) done; K(kt+1) (newest 4) stays in flight
    if (kt + 1 < 32)
      __asm__ volatile("s_waitcnt vmcnt(4)" ::: "memory");
    else
      __asm__ volatile("s_waitcnt vmcnt(0)" ::: "memory");
    __builtin_amdgcn_s_barrier();

    // O += P * V, vf reads shared by both halves
    __builtin_amdgcn_s_setprio(1);
#pragma unroll
    for (int kk2 = 0; kk2 < 2; ++kk2) {
#pragma unroll
      for (int dt = 0; dt < 8; ++dt) {
        bf16x8 vf = *(const bf16x8*)&Vs[(dt * 16 + l15) * 64 + ((kk2 * 4 + kq) ^ (l15 & 7)) * 8];
        o0[dt] = __builtin_amdgcn_mfma_f32_16x16x32_bf16(pf0[kk2], vf, o0[dt], 0, 0, 0);
        o1[dt] = __builtin_amdgcn_mfma_f32_16x16x32_bf16(pf1[kk2], vf, o1[dt], 0, 0, 0);
      }
    }
    __builtin_amdgcn_s_setprio(0);
  }

  // final lsum reduce over the 16-lane column groups (keys live across l15)
#pragma unroll
  for (int r = 0; r < 4; ++r) {
#pragma unroll
    for (int off = 1; off < 16; off <<= 1) {
      l0[r] += __shfl_xor(l0[r], off, 64);
      l1[r] += __shfl_xor(l1[r], off, 64);
    }
  }
#pragma unroll
  for (int r = 0; r < 4; ++r) {
    float i0 = 1.f / l0[r], i1 = 1.f / l1[r];
#pragma unroll
    for (int dt = 0; dt < 8; ++dt) {
      size_t idx = (size_t)(b * T_ + q0 + wid * 32 + kq * 4 + r) * D_ + h * HD_ + dt * 16 + l15;
      O[idx] = f2bf(o0[dt][r] * i0);
      O[idx + (size_t)16 * D_] = f2bf(o1[dt][r] * i1);
    }
  }
}

// ---------------- launch ----------------
extern "C" void kernel_launch(void* const* d_in, const int* in_sizes, int n_in,
                              void* d_out, int out_size, void* d_ws, size_t ws_size,
                              hipStream_t stream) {
  const float* x  = (const float*)d_in[0];
  const float* cs = (const float*)d_in[1];
  const float* sn = (const float*)d_in[2];
  const float* wq = (const float*)d_in[3];
  const float* bq = (const float*)d_in[4];
  const float* wk = (const float*)d_in[5];
  const float* bk = (const float*)d_in[6];
  const float* wv = (const float*)d_in[7];
  const float* bv = (const float*)d_in[8];
  const float* gq = (const float*)d_in[9];
  const float* gk = (const float*)d_in[10];
  const float* wo = (const float*)d_in[11];
  const float* bo = (const float*)d_in[12];
  const float* wg = (const float*)d_in[13];
  const float* bg = (const float*)d_in[14];

  char* ws = (char*)d_ws;
  const size_t SZ_BTD_BF = (size_t)BT_ * D_ * 2;   // 16 MB
  const size_t SZ_DD_BF  = (size_t)D_ * D_ * 2;    //  8 MB
  const size_t SZ_BTD_F  = (size_t)BT_ * D_ * 4;   // 32 MB

  size_t off = 0;
  ushort_t* xb  = (ushort_t*)(ws + off); off += SZ_BTD_BF;        // aliased as attn later
  ushort_t* wqT = (ushort_t*)(ws + off); off += SZ_DD_BF;
  ushort_t* wkT = (ushort_t*)(ws + off); off += SZ_DD_BF;
  ushort_t* wvT = (ushort_t*)(ws + off); off += SZ_DD_BF;
  ushort_t* woT = (ushort_t*)(ws + off); off += SZ_DD_BF;
  ushort_t* wgT = (ushort_t*)(ws + off); off += SZ_DD_BF;
  float*    qf  = (float*)(ws + off);    off += SZ_BTD_F;         // aliased as outf later
  float*    kf  = (float*)(ws + off);    off += SZ_BTD_F;         // aliased as outb later
  ushort_t* vb  = (ushort_t*)(ws + off); off += SZ_BTD_BF;
  ushort_t* qb  = (ushort_t*)(ws + off); off += SZ_BTD_BF;
  ushort_t* kb  = (ushort_t*)(ws + off); off += SZ_BTD_BF;
  ushort_t* vt  = (ushort_t*)(ws + off); off += SZ_BTD_BF;        // ~193 MB total
  ushort_t* attn = xb;            // xb dead after QKV GEMMs
  float*    outf = qf;            // qf dead after norm_rope(q)
  ushort_t* outb = (ushort_t*)kf; // kf dead after norm_rope(k)

  const float cl2 = 0.08838834764831845f * 1.4426950408889634f;  // 1/sqrt(128)*log2e

  k_cast_x<<<8192, 256, 0, stream>>>(x, xb);
  k_twT<<<dim3(64, 64), dim3(32, 8), 0, stream>>>(wq, wqT);
  k_twT<<<dim3(64, 64), dim3(32, 8), 0, stream>>>(wk, wkT);
  k_twT<<<dim3(64, 64), dim3(32, 8), 0, stream>>>(wv, wvT);
  k_twT<<<dim3(64, 64), dim3(32, 8), 0, stream>>>(wo, woT);
  k_twT<<<dim3(64, 64), dim3(32, 8), 0, stream>>>(wg, wgT);

  k_gemm<0><<<dim3(16, 32), 256, 0, stream>>>(xb, wqT, bq, qf, nullptr, nullptr);
  k_gemm<0><<<dim3(16, 32), 256, 0, stream>>>(xb, wkT, bk, kf, nullptr, nullptr);
  k_gemm<1><<<dim3(16, 32), 256, 0, stream>>>(xb, wvT, bv, nullptr, vb, nullptr);

  k_normrope<<<4096, 256, 0, stream>>>(qf, gq, cs, sn, qb, cl2);
  k_normrope<<<4096, 256, 0, stream>>>(kf, gk, cs, sn, kb, 1.0f);
  k_tv<<<dim3(4, 64, 32), dim3(32, 8), 0, stream>>>(vb, vt);

  k_flash<<<dim3(16, 32), 256, 0, stream>>>(qb, kb, vt, attn);

  k_gemm<2><<<dim3(16, 32), 256, 0, stream>>>(attn, woT, bo, outf, outb, nullptr);
  k_gemm<3><<<dim3(16, 32), 256, 0, stream>>>(outb, wgT, bg, (float*)d_out, nullptr, outf);
}

// Round 3
// 556.025 us; speedup vs baseline: 1.0889x; 1.0889x over previous
//
#include <hip/hip_runtime.h>
#include <stdint.h>

typedef unsigned short ushort_t;
typedef __attribute__((ext_vector_type(8))) short bf16x8;
typedef __attribute__((ext_vector_type(4))) float f32x4;
typedef __attribute__((ext_vector_type(4))) unsigned short u16x4;

#define B_ 2
#define T_ 2048
#define D_ 2048
#define H_ 16
#define HD_ 128
#define BT_ 4096

__device__ __forceinline__ ushort_t f2bf(float f) {
  unsigned u = __float_as_uint(f);
  u += 0x7FFFu + ((u >> 16) & 1u);   // RNE
  return (ushort_t)(u >> 16);
}

__device__ __forceinline__ void async16(const void* g, void* l) {
  __builtin_amdgcn_global_load_lds(
      (const __attribute__((address_space(1))) unsigned int*)g,
      (__attribute__((address_space(3))) unsigned int*)l, 16, 0, 0);
}

// ---------------- elementwise cast x -> bf16 ----------------
__global__ void k_cast_x(const float* __restrict__ in, ushort_t* __restrict__ out) {
  int i = blockIdx.x * 256 + threadIdx.x;          // 4 elements per thread
  float4 v = ((const float4*)in)[i];
  u16x4 r = { f2bf(v.x), f2bf(v.y), f2bf(v.z), f2bf(v.w) };
  ((u16x4*)out)[i] = r;
}

// ---------------- fused weight transpose+cast x5: w[K][N] f32 -> wt[N][K] bf16 ----------------
__global__ void k_twT5(const float* __restrict__ wa, const float* __restrict__ wb,
                       const float* __restrict__ wc, const float* __restrict__ wd,
                       const float* __restrict__ we,
                       ushort_t* __restrict__ ta, ushort_t* __restrict__ tb,
                       ushort_t* __restrict__ tc, ushort_t* __restrict__ td,
                       ushort_t* __restrict__ te) {
  const float* w; ushort_t* wt;
  switch (blockIdx.z) {
    case 0: w = wa; wt = ta; break;
    case 1: w = wb; wt = tb; break;
    case 2: w = wc; wt = tc; break;
    case 3: w = wd; wt = td; break;
    default: w = we; wt = te; break;
  }
  __shared__ float tile[32][33];
  int tx = threadIdx.x, ty = threadIdx.y;
  int x = blockIdx.x * 32 + tx;        // N index
  int y0 = blockIdx.y * 32;            // K index
#pragma unroll
  for (int k = 0; k < 4; ++k)
    tile[ty + k * 8][tx] = w[(size_t)(y0 + ty + k * 8) * D_ + x];
  __syncthreads();
  int ox = blockIdx.y * 32 + tx;       // K contiguous on write
  int oy0 = blockIdx.x * 32;           // N
#pragma unroll
  for (int k = 0; k < 4; ++k)
    wt[(size_t)(oy0 + ty + k * 8) * D_ + ox] = f2bf(tile[tx][ty + k * 8]);
}

// ---------------- GEMM: C[M=4096][N=2048] = A(bf16 MxK) * Bt(bf16 NxK)^T + bias ----------------
// Single-buffer (proven round-0 structure) with BK=64: grid=512 is exactly 2 blocks/CU
// (grid-limited occupancy), so 32 KB LDS is free; halves barrier/drain count per K-work.
// Staging swizzle: 8 chunks/row, gc = p ^ (row&7); row stride 128B = 32 banks ->
// reads hit 8 distinct chunk slots x 16 lanes = 2 lanes/bank-group (free, m136).
// EPI 0: store fp32.  1: store bf16.  2: store fp32 + bf16.  3: gate (out = aux*sigmoid(val))
template <int EPI>
__global__ __launch_bounds__(256) void k_gemm(
    const ushort_t* __restrict__ A, const ushort_t* __restrict__ Bt,
    const float* __restrict__ bias, float* __restrict__ outF,
    ushort_t* __restrict__ outB, const float* __restrict__ aux) {
  __shared__ __align__(16) short As[128 * 64];
  __shared__ __align__(16) short Bs[128 * 64];
  const int tid = threadIdx.x;
  const int wid = tid >> 6, lane = tid & 63;
  const int l15 = lane & 15, kq = lane >> 4;
  const int m0 = (wid >> 1) * 64, n0 = (wid & 1) * 64;
  const int tileM = blockIdx.y * 128, tileN = blockIdx.x * 128;

  f32x4 acc[4][4];
#pragma unroll
  for (int i = 0; i < 4; ++i)
#pragma unroll
    for (int j = 0; j < 4; ++j) acc[i][j] = (f32x4){0.f, 0.f, 0.f, 0.f};

  for (int k0 = 0; k0 < D_; k0 += 64) {
#pragma unroll
    for (int rr = 0; rr < 4; ++rr) {
      int c = rr * 256 + tid;
      int row = c >> 3, p = c & 7;
      int gc = p ^ (row & 7);          // XOR-swizzled global chunk (bank-conflict fix)
      async16(A + (size_t)(tileM + row) * D_ + k0 + gc * 8,
              &As[(rr * 256 + wid * 64) * 8]);
      async16(Bt + (size_t)(tileN + row) * D_ + k0 + gc * 8,
              &Bs[(rr * 256 + wid * 64) * 8]);
    }
    __syncthreads();
#pragma unroll
    for (int half = 0; half < 2; ++half) {
      bf16x8 a[4], b[4];
#pragma unroll
      for (int i = 0; i < 4; ++i) {
        int row = m0 + i * 16 + l15;
        a[i] = *(const bf16x8*)&As[row * 64 + ((half * 4 + kq) ^ (row & 7)) * 8];
      }
#pragma unroll
      for (int j = 0; j < 4; ++j) {
        int row = n0 + j * 16 + l15;
        b[j] = *(const bf16x8*)&Bs[row * 64 + ((half * 4 + kq) ^ (row & 7)) * 8];
      }
#pragma unroll
      for (int i = 0; i < 4; ++i)
#pragma unroll
        for (int j = 0; j < 4; ++j)
          acc[i][j] = __builtin_amdgcn_mfma_f32_16x16x32_bf16(a[i], b[j], acc[i][j], 0, 0, 0);
    }
    __syncthreads();
  }

#pragma unroll
  for (int i = 0; i < 4; ++i) {
#pragma unroll
    for (int j = 0; j < 4; ++j) {
#pragma unroll
      for (int r = 0; r < 4; ++r) {
        int gm = tileM + m0 + i * 16 + kq * 4 + r;   // C/D: row = quad*4 + reg
        int gn = tileN + n0 + j * 16 + l15;          //      col = lane&15
        size_t idx = (size_t)gm * D_ + gn;
        float val = acc[i][j][r] + bias[gn];
        if (EPI == 0) {
          outF[idx] = val;
        } else if (EPI == 1) {
          outB[idx] = f2bf(val);
        } else if (EPI == 2) {
          outF[idx] = val; outB[idx] = f2bf(val);
        } else {
          float sg = 1.f / (1.f + __expf(-val));
          outF[idx] = aux[idx] * sg;
        }
      }
    }
  }
}

// ---------------- fused RMSNorm (full D) + RoPE, fp32 in -> bf16 out (x oscale) ----------------
__global__ void k_normrope(const float* __restrict__ in, const float* __restrict__ g,
                           const float* __restrict__ cs, const float* __restrict__ sn,
                           ushort_t* __restrict__ out, float oscale) {
  const int row = blockIdx.x;            // 0..4095 = b*T + t
  const int t = row & (T_ - 1);
  const float* x = in + (size_t)row * D_;
  const int tid = threadIdx.x;
  float ss = 0.f;
#pragma unroll
  for (int i = tid; i < 512; i += 256) {
    float4 v = ((const float4*)x)[i];
    ss += v.x * v.x + v.y * v.y + v.z * v.z + v.w * v.w;
  }
#pragma unroll
  for (int off = 1; off < 64; off <<= 1) ss += __shfl_xor(ss, off, 64);
  __shared__ float part[4];
  if ((tid & 63) == 0) part[tid >> 6] = ss;
  __syncthreads();
  float rstd = rsqrtf((part[0] + part[1] + part[2] + part[3]) * (1.f / (float)D_) + 1e-6f);
  rstd *= oscale;                        // fold attention scale*log2e into Q
#pragma unroll
  for (int p = tid; p < 1024; p += 256) {
    int head = p >> 6, i = p & 63;
    int e1 = head * HD_ + i, e2 = e1 + 64;
    float x1 = x[e1] * rstd * g[e1];
    float x2 = x[e2] * rstd * g[e2];
    float c = cs[t * 64 + i], s = sn[t * 64 + i];
    out[(size_t)row * D_ + e1] = f2bf(x1 * c - s * x2);
    out[(size_t)row * D_ + e2] = f2bf(x2 * c + s * x1);
  }
}

// ---------------- V transpose per head: v[b][t][h*128+d] -> vt[bh][d][t] ----------------
__global__ void k_tv(const ushort_t* __restrict__ v, ushort_t* __restrict__ vt) {
  __shared__ ushort_t tile[32][33];
  int bh = blockIdx.z, b = bh >> 4, h = bh & 15;
  int tx = threadIdx.x, ty = threadIdx.y;
  int d = blockIdx.x * 32 + tx;
  int t0 = blockIdx.y * 32;
#pragma unroll
  for (int k = 0; k < 4; ++k)
    tile[ty + k * 8][tx] = v[(size_t)(b * T_ + t0 + ty + k * 8) * D_ + h * HD_ + d];
  __syncthreads();
  int ot = t0 + tx;
  int od0 = blockIdx.x * 32;
#pragma unroll
  for (int k = 0; k < 4; ++k)
    vt[((size_t)bh * HD_ + od0 + ty + k * 8) * T_ + ot] = tile[tx][ty + k * 8];
}

// ---------------- flash (round-1 proven): 128 q/block, fixed-max softmax, K double-buf,
// V single-buf, swizzled P, counted vmcnt, setprio, XCD swizzle ----------------
__global__ __launch_bounds__(256) void k_flash(
    const ushort_t* __restrict__ Q, const ushort_t* __restrict__ K,
    const ushort_t* __restrict__ Vt, ushort_t* __restrict__ O) {
  __shared__ __align__(16) short Ks[2][64 * 128];   // [buf][key][d]
  __shared__ __align__(16) short Vs[128 * 64];      // [d][key]
  __shared__ __align__(16) short Ps[4][32 * 64];    // per-wave P, XOR-swizzled chunks

  const int tid = threadIdx.x;
  const int wid = tid >> 6, lane = tid & 63;
  const int l15 = lane & 15, kq = lane >> 4;
  const int flat = blockIdx.y * gridDim.x + blockIdx.x;   // 512 blocks
  const int swz = (flat & 7) * 64 + (flat >> 3);          // bijective XCD chunking
  const int bh = swz >> 4, b = bh >> 4, h = bh & 15;
  const int q0 = (swz & 15) * 128;

  const ushort_t* kp[4];
  const ushort_t* vp[4];
#pragma unroll
  for (int rr = 0; rr < 4; ++rr) {
    int c = rr * 256 + tid;
    int krow = c >> 4, kc = (c & 15) ^ (krow & 15);
    kp[rr] = K + (size_t)(b * T_ + krow) * D_ + h * HD_ + kc * 8;
    int drow = c >> 3, vc = (c & 7) ^ (drow & 7);
    vp[rr] = Vt + ((size_t)bh * HD_ + drow) * T_ + vc * 8;
  }

  // Q A-frags, two 16-row halves (rows q0 + wid*32 + {0,16} + l15); scale pre-folded
  bf16x8 qa0[4], qa1[4];
  {
    const ushort_t* qp0 = Q + (size_t)(b * T_ + q0 + wid * 32 + l15) * D_ + h * HD_ + kq * 8;
    const ushort_t* qp1 = qp0 + 16 * D_;
#pragma unroll
    for (int kk = 0; kk < 4; ++kk) {
      qa0[kk] = *(const bf16x8*)(qp0 + kk * 32);
      qa1[kk] = *(const bf16x8*)(qp1 + kk * 32);
    }
  }

  f32x4 o0[8], o1[8];
#pragma unroll
  for (int dt = 0; dt < 8; ++dt) {
    o0[dt] = (f32x4){0.f, 0.f, 0.f, 0.f};
    o1[dt] = (f32x4){0.f, 0.f, 0.f, 0.f};
  }
  float l0[4] = {0.f, 0.f, 0.f, 0.f}, l1[4] = {0.f, 0.f, 0.f, 0.f};

  // prologue: stage K tile 0 into buf 0
#pragma unroll
  for (int rr = 0; rr < 4; ++rr)
    async16(kp[rr], &Ks[0][(rr * 256 + wid * 64) * 8]);

  for (int kt = 0; kt < 32; ++kt) {
    const int buf = kt & 1;
    // [A] my K(kt) loads done -> barrier -> all waves' K(kt) staged; fences V vs prior PV
    __asm__ volatile("s_waitcnt vmcnt(0)" ::: "memory");
    __builtin_amdgcn_s_barrier();

    // issue V(kt) FIRST, then K(kt+1): vmcnt(4) at [B] = "V done, K in flight"
#pragma unroll
    for (int rr = 0; rr < 4; ++rr)
      async16(vp[rr] + (size_t)kt * 64, &Vs[(rr * 256 + wid * 64) * 8]);
    if (kt + 1 < 32) {
#pragma unroll
      for (int rr = 0; rr < 4; ++rr)
        async16(kp[rr] + (size_t)(kt + 1) * 64 * D_, &Ks[buf ^ 1][(rr * 256 + wid * 64) * 8]);
    }

    // S = Q*K^T for both halves, sharing kf reads
    f32x4 s0[4], s1[4];
#pragma unroll
    for (int j = 0; j < 4; ++j) { s0[j] = (f32x4){0.f,0.f,0.f,0.f}; s1[j] = (f32x4){0.f,0.f,0.f,0.f}; }
    __builtin_amdgcn_s_setprio(1);
#pragma unroll
    for (int j = 0; j < 4; ++j) {
#pragma unroll
      for (int kk = 0; kk < 4; ++kk) {
        int row = j * 16 + l15;
        bf16x8 kf = *(const bf16x8*)&Ks[buf][row * 128 + ((kk * 4 + kq) ^ l15) * 8];
        s0[j] = __builtin_amdgcn_mfma_f32_16x16x32_bf16(qa0[kk], kf, s0[j], 0, 0, 0);
        s1[j] = __builtin_amdgcn_mfma_f32_16x16x32_bf16(qa1[kk], kf, s1[j], 0, 0, 0);
      }
    }
    __builtin_amdgcn_s_setprio(0);

    // fixed-max softmax (exp2 domain), per-lane partial sums, swizzled P store
#pragma unroll
    for (int r = 0; r < 4; ++r) {
      const int row0 = kq * 4 + r, row1 = row0 + 16;
      const int sw0 = (row0 & 7) ^ ((row0 & 8) >> 2);
      const int sw1 = (row1 & 7) ^ ((row1 & 8) >> 2);
#pragma unroll
      for (int j = 0; j < 4; ++j) {
        float p0 = __builtin_amdgcn_exp2f(s0[j][r]); l0[r] += p0;
        float p1 = __builtin_amdgcn_exp2f(s1[j][r]); l1[r] += p1;
        int c = j * 2 + (l15 >> 3);
        Ps[wid][row0 * 64 + (c ^ sw0) * 8 + (l15 & 7)] = (short)f2bf(p0);
        Ps[wid][row1 * 64 + (c ^ sw1) * 8 + (l15 & 7)] = (short)f2bf(p1);
      }
    }
    __asm__ volatile("s_waitcnt lgkmcnt(0)" ::: "memory");   // P writes -> cross-lane reads

    bf16x8 pf0[2], pf1[2];
#pragma unroll
    for (int kk2 = 0; kk2 < 2; ++kk2) {
      int r0 = l15, r1 = 16 + l15;
      int c0 = (kk2 * 4 + kq) ^ (r0 & 7) ^ ((r0 & 8) >> 2);
      int c1 = (kk2 * 4 + kq) ^ (r1 & 7) ^ ((r1 & 8) >> 2);
      pf0[kk2] = *(const bf16x8*)&Ps[wid][r0 * 64 + c0 * 8];
      pf1[kk2] = *(const bf16x8*)&Ps[wid][r1 * 64 + c1 * 8];
    }

    // [B] my V(kt) (oldest 4) done; K(kt+1) (newest 4) stays in flight
    if (kt + 1 < 32)
      __asm__ volatile("s_waitcnt vmcnt(4)" ::: "memory");
    else
      __asm__ volatile("s_waitcnt vmcnt(0)" ::: "memory");
    __builtin_amdgcn_s_barrier();

    // O += P * V, vf reads shared by both halves
    __builtin_amdgcn_s_setprio(1);
#pragma unroll
    for (int kk2 = 0; kk2 < 2; ++kk2) {
#pragma unroll
      for (int dt = 0; dt < 8; ++dt) {
        bf16x8 vf = *(const bf16x8*)&Vs[(dt * 16 + l15) * 64 + ((kk2 * 4 + kq) ^ (l15 & 7)) * 8];
        o0[dt] = __builtin_amdgcn_mfma_f32_16x16x32_bf16(pf0[kk2], vf, o0[dt], 0, 0, 0);
        o1[dt] = __builtin_amdgcn_mfma_f32_16x16x32_bf16(pf1[kk2], vf, o1[dt], 0, 0, 0);
      }
    }
    __builtin_amdgcn_s_setprio(0);
  }

  // final lsum reduce over the 16-lane column groups (keys live across l15)
#pragma unroll
  for (int r = 0; r < 4; ++r) {
#pragma unroll
    for (int off = 1; off < 16; off <<= 1) {
      l0[r] += __shfl_xor(l0[r], off, 64);
      l1[r] += __shfl_xor(l1[r], off, 64);
    }
  }
#pragma unroll
  for (int r = 0; r < 4; ++r) {
    float i0 = 1.f / l0[r], i1 = 1.f / l1[r];
#pragma unroll
    for (int dt = 0; dt < 8; ++dt) {
      size_t idx = (size_t)(b * T_ + q0 + wid * 32 + kq * 4 + r) * D_ + h * HD_ + dt * 16 + l15;
      O[idx] = f2bf(o0[dt][r] * i0);
      O[idx + (size_t)16 * D_] = f2bf(o1[dt][r] * i1);
    }
  }
}

// ---------------- launch ----------------
extern "C" void kernel_launch(void* const* d_in, const int* in_sizes, int n_in,
                              void* d_out, int out_size, void* d_ws, size_t ws_size,
                              hipStream_t stream) {
  const float* x  = (const float*)d_in[0];
  const float* cs = (const float*)d_in[1];
  const float* sn = (const float*)d_in[2];
  const float* wq = (const float*)d_in[3];
  const float* bq = (const float*)d_in[4];
  const float* wk = (const float*)d_in[5];
  const float* bk = (const float*)d_in[6];
  const float* wv = (const float*)d_in[7];
  const float* bv = (const float*)d_in[8];
  const float* gq = (const float*)d_in[9];
  const float* gk = (const float*)d_in[10];
  const float* wo = (const float*)d_in[11];
  const float* bo = (const float*)d_in[12];
  const float* wg = (const float*)d_in[13];
  const float* bg = (const float*)d_in[14];

  char* ws = (char*)d_ws;
  const size_t SZ_BTD_BF = (size_t)BT_ * D_ * 2;   // 16 MB
  const size_t SZ_DD_BF  = (size_t)D_ * D_ * 2;    //  8 MB
  const size_t SZ_BTD_F  = (size_t)BT_ * D_ * 4;   // 32 MB

  size_t off = 0;
  ushort_t* xb  = (ushort_t*)(ws + off); off += SZ_BTD_BF;        // aliased as attn later
  ushort_t* wqT = (ushort_t*)(ws + off); off += SZ_DD_BF;
  ushort_t* wkT = (ushort_t*)(ws + off); off += SZ_DD_BF;
  ushort_t* wvT = (ushort_t*)(ws + off); off += SZ_DD_BF;
  ushort_t* woT = (ushort_t*)(ws + off); off += SZ_DD_BF;
  ushort_t* wgT = (ushort_t*)(ws + off); off += SZ_DD_BF;
  float*    qf  = (float*)(ws + off);    off += SZ_BTD_F;         // aliased as outf later
  float*    kf  = (float*)(ws + off);    off += SZ_BTD_F;         // aliased as outb later
  ushort_t* vb  = (ushort_t*)(ws + off); off += SZ_BTD_BF;
  ushort_t* qb  = (ushort_t*)(ws + off); off += SZ_BTD_BF;
  ushort_t* kb  = (ushort_t*)(ws + off); off += SZ_BTD_BF;
  ushort_t* vt  = (ushort_t*)(ws + off); off += SZ_BTD_BF;        // ~193 MB total
  ushort_t* attn = xb;            // xb dead after QKV GEMMs
  float*    outf = qf;            // qf dead after norm_rope(q)
  ushort_t* outb = (ushort_t*)kf; // kf dead after norm_rope(k)

  const float cl2 = 0.08838834764831845f * 1.4426950408889634f;  // 1/sqrt(128)*log2e

  k_cast_x<<<8192, 256, 0, stream>>>(x, xb);
  k_twT5<<<dim3(64, 64, 5), dim3(32, 8), 0, stream>>>(wq, wk, wv, wo, wg,
                                                      wqT, wkT, wvT, woT, wgT);

  k_gemm<0><<<dim3(16, 32), 256, 0, stream>>>(xb, wqT, bq, qf, nullptr, nullptr);
  k_gemm<0><<<dim3(16, 32), 256, 0, stream>>>(xb, wkT, bk, kf, nullptr, nullptr);
  k_gemm<1><<<dim3(16, 32), 256, 0, stream>>>(xb, wvT, bv, nullptr, vb, nullptr);

  k_normrope<<<4096, 256, 0, stream>>>(qf, gq, cs, sn, qb, cl2);
  k_normrope<<<4096, 256, 0, stream>>>(kf, gk, cs, sn, kb, 1.0f);
  k_tv<<<dim3(4, 64, 32), dim3(32, 8), 0, stream>>>(vb, vt);

  k_flash<<<dim3(16, 32), 256, 0, stream>>>(qb, kb, vt, attn);

  k_gemm<2><<<dim3(16, 32), 256, 0, stream>>>(attn, woT, bo, outf, outb, nullptr);
  k_gemm<3><<<dim3(16, 32), 256, 0, stream>>>(outb, wgT, bg, (float*)d_out, nullptr, outf);
}

// Round 4
// 532.083 us; speedup vs baseline: 1.1379x; 1.0450x over previous
//
#include <hip/hip_runtime.h>
#include <stdint.h>

typedef unsigned short ushort_t;
typedef __attribute__((ext_vector_type(8))) short bf16x8;
typedef __attribute__((ext_vector_type(4))) float f32x4;
typedef __attribute__((ext_vector_type(4))) unsigned short u16x4;

#define B_ 2
#define T_ 2048
#define D_ 2048
#define H_ 16
#define HD_ 128
#define BT_ 4096

__device__ __forceinline__ ushort_t f2bf(float f) {
  unsigned u = __float_as_uint(f);
  u += 0x7FFFu + ((u >> 16) & 1u);   // RNE
  return (ushort_t)(u >> 16);
}

__device__ __forceinline__ void async16(const void* g, void* l) {
  __builtin_amdgcn_global_load_lds(
      (const __attribute__((address_space(1))) unsigned int*)g,
      (__attribute__((address_space(3))) unsigned int*)l, 16, 0, 0);
}

// ---------------- elementwise cast x -> bf16 ----------------
__global__ void k_cast_x(const float* __restrict__ in, ushort_t* __restrict__ out) {
  int i = blockIdx.x * 256 + threadIdx.x;          // 4 elements per thread
  float4 v = ((const float4*)in)[i];
  u16x4 r = { f2bf(v.x), f2bf(v.y), f2bf(v.z), f2bf(v.w) };
  ((u16x4*)out)[i] = r;
}

// ---------------- fused weight transpose+cast x5: w[K][N] f32 -> wt[N][K] bf16 ----------------
__global__ void k_twT5(const float* __restrict__ wa, const float* __restrict__ wb,
                       const float* __restrict__ wc, const float* __restrict__ wd,
                       const float* __restrict__ we,
                       ushort_t* __restrict__ ta, ushort_t* __restrict__ tb,
                       ushort_t* __restrict__ tc, ushort_t* __restrict__ td,
                       ushort_t* __restrict__ te) {
  const float* w; ushort_t* wt;
  switch (blockIdx.z) {
    case 0: w = wa; wt = ta; break;
    case 1: w = wb; wt = tb; break;
    case 2: w = wc; wt = tc; break;
    case 3: w = wd; wt = td; break;
    default: w = we; wt = te; break;
  }
  __shared__ float tile[32][33];
  int tx = threadIdx.x, ty = threadIdx.y;
  int x = blockIdx.x * 32 + tx;        // N index
  int y0 = blockIdx.y * 32;            // K index
#pragma unroll
  for (int k = 0; k < 4; ++k)
    tile[ty + k * 8][tx] = w[(size_t)(y0 + ty + k * 8) * D_ + x];
  __syncthreads();
  int ox = blockIdx.y * 32 + tx;       // K contiguous on write
  int oy0 = blockIdx.x * 32;           // N
#pragma unroll
  for (int k = 0; k < 4; ++k)
    wt[(size_t)(oy0 + ty + k * 8) * D_ + ox] = f2bf(tile[tx][ty + k * 8]);
}

// ---------------- GEMM: C[M=4096][N=2048] = A(bf16 MxK) * Bt(bf16 NxK)^T + bias ----------------
// Single-buffer, BK=64 (proven round-3). EPI 0: fp32. 1: bf16. 2: both. 3: gate.
template <int EPI>
__global__ __launch_bounds__(256) void k_gemm(
    const ushort_t* __restrict__ A, const ushort_t* __restrict__ Bt,
    const float* __restrict__ bias, float* __restrict__ outF,
    ushort_t* __restrict__ outB, const float* __restrict__ aux) {
  __shared__ __align__(16) short As[128 * 64];
  __shared__ __align__(16) short Bs[128 * 64];
  const int tid = threadIdx.x;
  const int wid = tid >> 6, lane = tid & 63;
  const int l15 = lane & 15, kq = lane >> 4;
  const int m0 = (wid >> 1) * 64, n0 = (wid & 1) * 64;
  const int tileM = blockIdx.y * 128, tileN = blockIdx.x * 128;

  f32x4 acc[4][4];
#pragma unroll
  for (int i = 0; i < 4; ++i)
#pragma unroll
    for (int j = 0; j < 4; ++j) acc[i][j] = (f32x4){0.f, 0.f, 0.f, 0.f};

  for (int k0 = 0; k0 < D_; k0 += 64) {
#pragma unroll
    for (int rr = 0; rr < 4; ++rr) {
      int c = rr * 256 + tid;
      int row = c >> 3, p = c & 7;
      int gc = p ^ (row & 7);          // XOR-swizzled global chunk (bank-conflict fix)
      async16(A + (size_t)(tileM + row) * D_ + k0 + gc * 8,
              &As[(rr * 256 + wid * 64) * 8]);
      async16(Bt + (size_t)(tileN + row) * D_ + k0 + gc * 8,
              &Bs[(rr * 256 + wid * 64) * 8]);
    }
    __syncthreads();
#pragma unroll
    for (int half = 0; half < 2; ++half) {
      bf16x8 a[4], b[4];
#pragma unroll
      for (int i = 0; i < 4; ++i) {
        int row = m0 + i * 16 + l15;
        a[i] = *(const bf16x8*)&As[row * 64 + ((half * 4 + kq) ^ (row & 7)) * 8];
      }
#pragma unroll
      for (int j = 0; j < 4; ++j) {
        int row = n0 + j * 16 + l15;
        b[j] = *(const bf16x8*)&Bs[row * 64 + ((half * 4 + kq) ^ (row & 7)) * 8];
      }
#pragma unroll
      for (int i = 0; i < 4; ++i)
#pragma unroll
        for (int j = 0; j < 4; ++j)
          acc[i][j] = __builtin_amdgcn_mfma_f32_16x16x32_bf16(a[i], b[j], acc[i][j], 0, 0, 0);
    }
    __syncthreads();
  }

#pragma unroll
  for (int i = 0; i < 4; ++i) {
#pragma unroll
    for (int j = 0; j < 4; ++j) {
#pragma unroll
      for (int r = 0; r < 4; ++r) {
        int gm = tileM + m0 + i * 16 + kq * 4 + r;   // C/D: row = quad*4 + reg
        int gn = tileN + n0 + j * 16 + l15;          //      col = lane&15
        size_t idx = (size_t)gm * D_ + gn;
        float val = acc[i][j][r] + bias[gn];
        if (EPI == 0) {
          outF[idx] = val;
        } else if (EPI == 1) {
          outB[idx] = f2bf(val);
        } else if (EPI == 2) {
          outF[idx] = val; outB[idx] = f2bf(val);
        } else {
          float sg = 1.f / (1.f + __expf(-val));
          outF[idx] = aux[idx] * sg;
        }
      }
    }
  }
}

// ---------------- fused RMSNorm (full D) + RoPE, fp32 in -> bf16 out (x oscale) ----------------
__global__ void k_normrope(const float* __restrict__ in, const float* __restrict__ g,
                           const float* __restrict__ cs, const float* __restrict__ sn,
                           ushort_t* __restrict__ out, float oscale) {
  const int row = blockIdx.x;            // 0..4095 = b*T + t
  const int t = row & (T_ - 1);
  const float* x = in + (size_t)row * D_;
  const int tid = threadIdx.x;
  float ss = 0.f;
#pragma unroll
  for (int i = tid; i < 512; i += 256) {
    float4 v = ((const float4*)x)[i];
    ss += v.x * v.x + v.y * v.y + v.z * v.z + v.w * v.w;
  }
#pragma unroll
  for (int off = 1; off < 64; off <<= 1) ss += __shfl_xor(ss, off, 64);
  __shared__ float part[4];
  if ((tid & 63) == 0) part[tid >> 6] = ss;
  __syncthreads();
  float rstd = rsqrtf((part[0] + part[1] + part[2] + part[3]) * (1.f / (float)D_) + 1e-6f);
  rstd *= oscale;                        // fold attention scale*log2e into Q
#pragma unroll
  for (int p = tid; p < 1024; p += 256) {
    int head = p >> 6, i = p & 63;
    int e1 = head * HD_ + i, e2 = e1 + 64;
    float x1 = x[e1] * rstd * g[e1];
    float x2 = x[e2] * rstd * g[e2];
    float c = cs[t * 64 + i], s = sn[t * 64 + i];
    out[(size_t)row * D_ + e1] = f2bf(x1 * c - s * x2);
    out[(size_t)row * D_ + e2] = f2bf(x2 * c + s * x1);
  }
}

// ---------------- V transpose per head: v[b][t][h*128+d] -> vt[bh][d][t] ----------------
__global__ void k_tv(const ushort_t* __restrict__ v, ushort_t* __restrict__ vt) {
  __shared__ ushort_t tile[32][33];
  int bh = blockIdx.z, b = bh >> 4, h = bh & 15;
  int tx = threadIdx.x, ty = threadIdx.y;
  int d = blockIdx.x * 32 + tx;
  int t0 = blockIdx.y * 32;
#pragma unroll
  for (int k = 0; k < 4; ++k)
    tile[ty + k * 8][tx] = v[(size_t)(b * T_ + t0 + ty + k * 8) * D_ + h * HD_ + d];
  __syncthreads();
  int ot = t0 + tx;
  int od0 = blockIdx.x * 32;
#pragma unroll
  for (int k = 0; k < 4; ++k)
    vt[((size_t)bh * HD_ + od0 + ty + k * 8) * T_ + ot] = tile[tx][ty + k * 8];
}

// ---------------- flash v6: QBLK=64, KVBLK=32 for occupancy (28 KB LDS, grid 1024
// = 4 blocks/CU = 16 waves/CU vs prior 1 block/4 waves at 64 KB). Same proven
// schedule: fixed-max softmax, K double-buf, V single-buf staged under QK, counted
// vmcnt, setprio, XCD swizzle. Swizzles re-derived for halved row strides:
// Vs/Ps row=64B -> ^((row>>1)&3); Ks row=256B -> ^l15 over 16 chunks.
__global__ __launch_bounds__(256) void k_flash(
    const ushort_t* __restrict__ Q, const ushort_t* __restrict__ K,
    const ushort_t* __restrict__ Vt, ushort_t* __restrict__ O) {
  __shared__ __align__(16) short Ks[2][32 * 128];   // [buf][key][d]   8 KB each
  __shared__ __align__(16) short Vs[128 * 32];      // [d][key]        8 KB
  __shared__ __align__(16) short Ps[4][16 * 32];    // per-wave P      4 KB

  const int tid = threadIdx.x;
  const int wid = tid >> 6, lane = tid & 63;
  const int l15 = lane & 15, kq = lane >> 4;
  const int flat = blockIdx.y * gridDim.x + blockIdx.x;   // 1024 blocks
  const int swz = (flat & 7) * 128 + (flat >> 3);         // bijective XCD chunking
  const int bh = swz >> 5, b = bh >> 4, h = bh & 15;
  const int q0 = (swz & 31) * 64;

  const ushort_t* kp[2];
  const ushort_t* vp[2];
#pragma unroll
  for (int rr = 0; rr < 2; ++rr) {
    int c = rr * 256 + tid;
    int krow = c >> 4, kc = (c & 15) ^ (krow & 15);       // 16 chunks/row (128 d)
    kp[rr] = K + (size_t)(b * T_ + krow) * D_ + h * HD_ + kc * 8;
    int drow = c >> 2, vc = (c & 3) ^ ((drow >> 1) & 3);  // 4 chunks/row (32 keys)
    vp[rr] = Vt + ((size_t)bh * HD_ + drow) * T_ + vc * 8;
  }

  // Q A-frags: wave owns 16 q-rows (q0 + wid*16 + l15); scale pre-folded
  bf16x8 qa[4];
  {
    const ushort_t* qp = Q + (size_t)(b * T_ + q0 + wid * 16 + l15) * D_ + h * HD_ + kq * 8;
#pragma unroll
    for (int kk = 0; kk < 4; ++kk) qa[kk] = *(const bf16x8*)(qp + kk * 32);
  }

  f32x4 o[8];
#pragma unroll
  for (int dt = 0; dt < 8; ++dt) o[dt] = (f32x4){0.f, 0.f, 0.f, 0.f};
  float l[4] = {0.f, 0.f, 0.f, 0.f};

  // prologue: stage K tile 0 into buf 0 (2 wave-insts)
#pragma unroll
  for (int rr = 0; rr < 2; ++rr)
    async16(kp[rr], &Ks[0][(rr * 256 + wid * 64) * 8]);

  for (int kt = 0; kt < 64; ++kt) {
    const int buf = kt & 1;
    // [A] K(kt) staged for all waves; fences V staging below vs prior PV reads
    __asm__ volatile("s_waitcnt vmcnt(0)" ::: "memory");
    __builtin_amdgcn_s_barrier();

    // V(kt) first (2), K(kt+1) second (2): vmcnt(2) at [B] = V done, K in flight
#pragma unroll
    for (int rr = 0; rr < 2; ++rr)
      async16(vp[rr] + (size_t)kt * 32, &Vs[(rr * 256 + wid * 64) * 8]);
    if (kt + 1 < 64) {
#pragma unroll
      for (int rr = 0; rr < 2; ++rr)
        async16(kp[rr] + (size_t)(kt + 1) * 32 * D_, &Ks[buf ^ 1][(rr * 256 + wid * 64) * 8]);
    }

    // S = Q*K^T: rows = 16 q, cols = 32 keys (j*16+l15)
    f32x4 s[2];
    s[0] = (f32x4){0.f, 0.f, 0.f, 0.f};
    s[1] = (f32x4){0.f, 0.f, 0.f, 0.f};
    __builtin_amdgcn_s_setprio(1);
#pragma unroll
    for (int j = 0; j < 2; ++j) {
#pragma unroll
      for (int kk = 0; kk < 4; ++kk) {
        int row = j * 16 + l15;
        bf16x8 kf = *(const bf16x8*)&Ks[buf][row * 128 + ((kk * 4 + kq) ^ l15) * 8];
        s[j] = __builtin_amdgcn_mfma_f32_16x16x32_bf16(qa[kk], kf, s[j], 0, 0, 0);
      }
    }
    __builtin_amdgcn_s_setprio(0);

    // fixed-max softmax (exp2 domain), per-lane partials, swizzled P store
#pragma unroll
    for (int r = 0; r < 4; ++r) {
      const int row = kq * 4 + r;              // q-row 0..15
      const int sw = (row >> 1) & 3;
#pragma unroll
      for (int j = 0; j < 2; ++j) {
        float p = __builtin_amdgcn_exp2f(s[j][r]);
        l[r] += p;
        int c = j * 2 + (l15 >> 3);            // key chunk 0..3
        Ps[wid][row * 32 + ((c ^ sw) & 3) * 8 + (l15 & 7)] = (short)f2bf(p);
      }
    }
    __asm__ volatile("s_waitcnt lgkmcnt(0)" ::: "memory");   // P writes -> cross-lane reads

    // P A-frag: rows l15, keys chunk kq (stored at kq ^ sw(l15))
    bf16x8 pf = *(const bf16x8*)&Ps[wid][l15 * 32 + (kq ^ ((l15 >> 1) & 3)) * 8];

    // [B] V(kt) (oldest 2) done; K(kt+1) (newest 2) stays in flight
    if (kt + 1 < 64)
      __asm__ volatile("s_waitcnt vmcnt(2)" ::: "memory");
    else
      __asm__ volatile("s_waitcnt vmcnt(0)" ::: "memory");
    __builtin_amdgcn_s_barrier();

    // O += P * V
    __builtin_amdgcn_s_setprio(1);
#pragma unroll
    for (int dt = 0; dt < 8; ++dt) {
      bf16x8 vf = *(const bf16x8*)&Vs[(dt * 16 + l15) * 32 + (kq ^ ((l15 >> 1) & 3)) * 8];
      o[dt] = __builtin_amdgcn_mfma_f32_16x16x32_bf16(pf, vf, o[dt], 0, 0, 0);
    }
    __builtin_amdgcn_s_setprio(0);
  }

  // denominators: keys live across l15 (16 lanes) for fixed kq
#pragma unroll
  for (int r = 0; r < 4; ++r) {
#pragma unroll
    for (int off = 1; off < 16; off <<= 1) l[r] += __shfl_xor(l[r], off, 64);
  }
#pragma unroll
  for (int r = 0; r < 4; ++r) {
    float inv = 1.f / l[r];
#pragma unroll
    for (int dt = 0; dt < 8; ++dt) {
      size_t idx = (size_t)(b * T_ + q0 + wid * 16 + kq * 4 + r) * D_ + h * HD_ + dt * 16 + l15;
      O[idx] = f2bf(o[dt][r] * inv);
    }
  }
}

// ---------------- launch ----------------
extern "C" void kernel_launch(void* const* d_in, const int* in_sizes, int n_in,
                              void* d_out, int out_size, void* d_ws, size_t ws_size,
                              hipStream_t stream) {
  const float* x  = (const float*)d_in[0];
  const float* cs = (const float*)d_in[1];
  const float* sn = (const float*)d_in[2];
  const float* wq = (const float*)d_in[3];
  const float* bq = (const float*)d_in[4];
  const float* wk = (const float*)d_in[5];
  const float* bk = (const float*)d_in[6];
  const float* wv = (const float*)d_in[7];
  const float* bv = (const float*)d_in[8];
  const float* gq = (const float*)d_in[9];
  const float* gk = (const float*)d_in[10];
  const float* wo = (const float*)d_in[11];
  const float* bo = (const float*)d_in[12];
  const float* wg = (const float*)d_in[13];
  const float* bg = (const float*)d_in[14];

  char* ws = (char*)d_ws;
  const size_t SZ_BTD_BF = (size_t)BT_ * D_ * 2;   // 16 MB
  const size_t SZ_DD_BF  = (size_t)D_ * D_ * 2;    //  8 MB
  const size_t SZ_BTD_F  = (size_t)BT_ * D_ * 4;   // 32 MB

  size_t off = 0;
  ushort_t* xb  = (ushort_t*)(ws + off); off += SZ_BTD_BF;        // aliased as attn later
  ushort_t* wqT = (ushort_t*)(ws + off); off += SZ_DD_BF;
  ushort_t* wkT = (ushort_t*)(ws + off); off += SZ_DD_BF;
  ushort_t* wvT = (ushort_t*)(ws + off); off += SZ_DD_BF;
  ushort_t* woT = (ushort_t*)(ws + off); off += SZ_DD_BF;
  ushort_t* wgT = (ushort_t*)(ws + off); off += SZ_DD_BF;
  float*    qf  = (float*)(ws + off);    off += SZ_BTD_F;         // aliased as outf later
  float*    kf  = (float*)(ws + off);    off += SZ_BTD_F;         // aliased as outb later
  ushort_t* vb  = (ushort_t*)(ws + off); off += SZ_BTD_BF;
  ushort_t* qb  = (ushort_t*)(ws + off); off += SZ_BTD_BF;
  ushort_t* kb  = (ushort_t*)(ws + off); off += SZ_BTD_BF;
  ushort_t* vt  = (ushort_t*)(ws + off); off += SZ_BTD_BF;        // ~193 MB total
  ushort_t* attn = xb;            // xb dead after QKV GEMMs
  float*    outf = qf;            // qf dead after norm_rope(q)
  ushort_t* outb = (ushort_t*)kf; // kf dead after norm_rope(k)

  const float cl2 = 0.08838834764831845f * 1.4426950408889634f;  // 1/sqrt(128)*log2e

  k_cast_x<<<8192, 256, 0, stream>>>(x, xb);
  k_twT5<<<dim3(64, 64, 5), dim3(32, 8), 0, stream>>>(wq, wk, wv, wo, wg,
                                                      wqT, wkT, wvT, woT, wgT);

  k_gemm<0><<<dim3(16, 32), 256, 0, stream>>>(xb, wqT, bq, qf, nullptr, nullptr);
  k_gemm<0><<<dim3(16, 32), 256, 0, stream>>>(xb, wkT, bk, kf, nullptr, nullptr);
  k_gemm<1><<<dim3(16, 32), 256, 0, stream>>>(xb, wvT, bv, nullptr, vb, nullptr);

  k_normrope<<<4096, 256, 0, stream>>>(qf, gq, cs, sn, qb, cl2);
  k_normrope<<<4096, 256, 0, stream>>>(kf, gk, cs, sn, kb, 1.0f);
  k_tv<<<dim3(4, 64, 32), dim3(32, 8), 0, stream>>>(vb, vt);

  k_flash<<<dim3(32, 32), 256, 0, stream>>>(qb, kb, vt, attn);

  k_gemm<2><<<dim3(16, 32), 256, 0, stream>>>(attn, woT, bo, outf, outb, nullptr);
  k_gemm<3><<<dim3(16, 32), 256, 0, stream>>>(outb, wgT, bg, (float*)d_out, nullptr, outf);
}

// Round 5
// 523.995 us; speedup vs baseline: 1.1555x; 1.0154x over previous
//
#include <hip/hip_runtime.h>
#include <stdint.h>

typedef unsigned short ushort_t;
typedef __attribute__((ext_vector_type(8))) short bf16x8;
typedef __attribute__((ext_vector_type(4))) float f32x4;
typedef __attribute__((ext_vector_type(4))) unsigned short u16x4;

#define B_ 2
#define T_ 2048
#define D_ 2048
#define H_ 16
#define HD_ 128
#define BT_ 4096

__device__ __forceinline__ ushort_t f2bf(float f) {
  unsigned u = __float_as_uint(f);
  u += 0x7FFFu + ((u >> 16) & 1u);   // RNE
  return (ushort_t)(u >> 16);
}

__device__ __forceinline__ void async16(const void* g, void* l) {
  __builtin_amdgcn_global_load_lds(
      (const __attribute__((address_space(1))) unsigned int*)g,
      (__attribute__((address_space(3))) unsigned int*)l, 16, 0, 0);
}

// ---------------- elementwise cast x -> bf16 ----------------
__global__ void k_cast_x(const float* __restrict__ in, ushort_t* __restrict__ out) {
  int i = blockIdx.x * 256 + threadIdx.x;          // 4 elements per thread
  float4 v = ((const float4*)in)[i];
  u16x4 r = { f2bf(v.x), f2bf(v.y), f2bf(v.z), f2bf(v.w) };
  ((u16x4*)out)[i] = r;
}

// ---------------- fused weight transpose+cast x5: w[K][N] f32 -> wt[N][K] bf16 ----------------
__global__ void k_twT5(const float* __restrict__ wa, const float* __restrict__ wb,
                       const float* __restrict__ wc, const float* __restrict__ wd,
                       const float* __restrict__ we,
                       ushort_t* __restrict__ ta, ushort_t* __restrict__ tb,
                       ushort_t* __restrict__ tc, ushort_t* __restrict__ td,
                       ushort_t* __restrict__ te) {
  const float* w; ushort_t* wt;
  switch (blockIdx.z) {
    case 0: w = wa; wt = ta; break;
    case 1: w = wb; wt = tb; break;
    case 2: w = wc; wt = tc; break;
    case 3: w = wd; wt = td; break;
    default: w = we; wt = te; break;
  }
  __shared__ float tile[32][33];
  int tx = threadIdx.x, ty = threadIdx.y;
  int x = blockIdx.x * 32 + tx;        // N index
  int y0 = blockIdx.y * 32;            // K index
#pragma unroll
  for (int k = 0; k < 4; ++k)
    tile[ty + k * 8][tx] = w[(size_t)(y0 + ty + k * 8) * D_ + x];
  __syncthreads();
  int ox = blockIdx.y * 32 + tx;       // K contiguous on write
  int oy0 = blockIdx.x * 32;           // N
#pragma unroll
  for (int k = 0; k < 4; ++k)
    wt[(size_t)(oy0 + ty + k * 8) * D_ + ox] = f2bf(tile[tx][ty + k * 8]);
}

// ---------------- GEMM: C[M=4096][N=2048] = A(bf16 MxK) * Bt(bf16 NxK)^T + bias ----------------
// BK=64, double-buffered, ONE vmcnt(0)+barrier per K-step at iteration top: the drain
// covers loads issued one full compute body earlier. No block swizzle (natural order
// preserves N-adjacent A-panel sharing; round-1 swizzle regressed). 64 KB LDS is free:
// grid=512 -> 2 blocks/CU regardless (2x64=128 <= 160).
// EPI 0: fp32. 1: bf16. 2: both. 3: gate (out = aux*sigmoid(val))
template <int EPI>
__global__ __launch_bounds__(256) void k_gemm(
    const ushort_t* __restrict__ A, const ushort_t* __restrict__ Bt,
    const float* __restrict__ bias, float* __restrict__ outF,
    ushort_t* __restrict__ outB, const float* __restrict__ aux) {
  __shared__ __align__(16) short As[2][128 * 64];
  __shared__ __align__(16) short Bs[2][128 * 64];
  const int tid = threadIdx.x;
  const int wid = tid >> 6, lane = tid & 63;
  const int l15 = lane & 15, kq = lane >> 4;
  const int m0 = (wid >> 1) * 64, n0 = (wid & 1) * 64;
  const int tileM = blockIdx.y * 128, tileN = blockIdx.x * 128;

  f32x4 acc[4][4];
#pragma unroll
  for (int i = 0; i < 4; ++i)
#pragma unroll
    for (int j = 0; j < 4; ++j) acc[i][j] = (f32x4){0.f, 0.f, 0.f, 0.f};

  auto stage = [&](int sbuf, int k0) {
#pragma unroll
    for (int rr = 0; rr < 4; ++rr) {
      int c = rr * 256 + tid;
      int row = c >> 3, p = c & 7;
      int gc = p ^ (row & 7);          // XOR-swizzled global chunk (bank-conflict fix)
      async16(A + (size_t)(tileM + row) * D_ + k0 + gc * 8,
              &As[sbuf][(rr * 256 + wid * 64) * 8]);
      async16(Bt + (size_t)(tileN + row) * D_ + k0 + gc * 8,
              &Bs[sbuf][(rr * 256 + wid * 64) * 8]);
    }
  };

  stage(0, 0);
  for (int k0 = 0; k0 < D_; k0 += 64) {
    const int buf = (k0 >> 6) & 1;
    // my stage of [buf] (issued last iter) done; barrier -> everyone's done.
    __asm__ volatile("s_waitcnt vmcnt(0)" ::: "memory");
    __builtin_amdgcn_s_barrier();
    if (k0 + 64 < D_) stage(buf ^ 1, k0 + 64);   // lands during compute below
#pragma unroll
    for (int half = 0; half < 2; ++half) {
      bf16x8 a[4], b[4];
#pragma unroll
      for (int i = 0; i < 4; ++i) {
        int row = m0 + i * 16 + l15;
        a[i] = *(const bf16x8*)&As[buf][row * 64 + ((half * 4 + kq) ^ (row & 7)) * 8];
      }
#pragma unroll
      for (int j = 0; j < 4; ++j) {
        int row = n0 + j * 16 + l15;
        b[j] = *(const bf16x8*)&Bs[buf][row * 64 + ((half * 4 + kq) ^ (row & 7)) * 8];
      }
#pragma unroll
      for (int i = 0; i < 4; ++i)
#pragma unroll
        for (int j = 0; j < 4; ++j)
          acc[i][j] = __builtin_amdgcn_mfma_f32_16x16x32_bf16(a[i], b[j], acc[i][j], 0, 0, 0);
    }
  }

#pragma unroll
  for (int i = 0; i < 4; ++i) {
#pragma unroll
    for (int j = 0; j < 4; ++j) {
#pragma unroll
      for (int r = 0; r < 4; ++r) {
        int gm = tileM + m0 + i * 16 + kq * 4 + r;   // C/D: row = quad*4 + reg
        int gn = tileN + n0 + j * 16 + l15;          //      col = lane&15
        size_t idx = (size_t)gm * D_ + gn;
        float val = acc[i][j][r] + bias[gn];
        if (EPI == 0) {
          outF[idx] = val;
        } else if (EPI == 1) {
          outB[idx] = f2bf(val);
        } else if (EPI == 2) {
          outF[idx] = val; outB[idx] = f2bf(val);
        } else {
          float sg = 1.f / (1.f + __expf(-val));
          outF[idx] = aux[idx] * sg;
        }
      }
    }
  }
}

// ---------------- fused RMSNorm (full D) + RoPE, fp32 in -> bf16 out (x oscale) ----------------
__global__ void k_normrope(const float* __restrict__ in, const float* __restrict__ g,
                           const float* __restrict__ cs, const float* __restrict__ sn,
                           ushort_t* __restrict__ out, float oscale) {
  const int row = blockIdx.x;            // 0..4095 = b*T + t
  const int t = row & (T_ - 1);
  const float* x = in + (size_t)row * D_;
  const int tid = threadIdx.x;
  float ss = 0.f;
#pragma unroll
  for (int i = tid; i < 512; i += 256) {
    float4 v = ((const float4*)x)[i];
    ss += v.x * v.x + v.y * v.y + v.z * v.z + v.w * v.w;
  }
#pragma unroll
  for (int off = 1; off < 64; off <<= 1) ss += __shfl_xor(ss, off, 64);
  __shared__ float part[4];
  if ((tid & 63) == 0) part[tid >> 6] = ss;
  __syncthreads();
  float rstd = rsqrtf((part[0] + part[1] + part[2] + part[3]) * (1.f / (float)D_) + 1e-6f);
  rstd *= oscale;                        // fold attention scale*log2e into Q
#pragma unroll
  for (int p = tid; p < 1024; p += 256) {
    int head = p >> 6, i = p & 63;
    int e1 = head * HD_ + i, e2 = e1 + 64;
    float x1 = x[e1] * rstd * g[e1];
    float x2 = x[e2] * rstd * g[e2];
    float c = cs[t * 64 + i], s = sn[t * 64 + i];
    out[(size_t)row * D_ + e1] = f2bf(x1 * c - s * x2);
    out[(size_t)row * D_ + e2] = f2bf(x2 * c + s * x1);
  }
}

// ---------------- V transpose per head: v[b][t][h*128+d] -> vt[bh][d][t] ----------------
__global__ void k_tv(const ushort_t* __restrict__ v, ushort_t* __restrict__ vt) {
  __shared__ ushort_t tile[32][33];
  int bh = blockIdx.z, b = bh >> 4, h = bh & 15;
  int tx = threadIdx.x, ty = threadIdx.y;
  int d = blockIdx.x * 32 + tx;
  int t0 = blockIdx.y * 32;
#pragma unroll
  for (int k = 0; k < 4; ++k)
    tile[ty + k * 8][tx] = v[(size_t)(b * T_ + t0 + ty + k * 8) * D_ + h * HD_ + d];
  __syncthreads();
  int ot = t0 + tx;
  int od0 = blockIdx.x * 32;
#pragma unroll
  for (int k = 0; k < 4; ++k)
    vt[((size_t)bh * HD_ + od0 + ty + k * 8) * T_ + ot] = tile[tx][ty + k * 8];
}

// ---------------- flash v7: QBLK=64, KVBLK=32, BOTH K and V double-buffered ->
// ONE vmcnt(0)+barrier per iteration (was 2); the drain covers loads that had the
// whole previous QK+softmax+PV body to land. 36 KB LDS -> still 4 blocks/CU
// (4x36=144<=160). Fixed-max softmax, setprio, XCD swizzle kept. ----------------
__global__ __launch_bounds__(256) void k_flash(
    const ushort_t* __restrict__ Q, const ushort_t* __restrict__ K,
    const ushort_t* __restrict__ Vt, ushort_t* __restrict__ O) {
  __shared__ __align__(16) short Ks[2][32 * 128];   // [buf][key][d]   8 KB each
  __shared__ __align__(16) short Vs[2][128 * 32];   // [buf][d][key]   8 KB each
  __shared__ __align__(16) short Ps[4][16 * 32];    // per-wave P      4 KB

  const int tid = threadIdx.x;
  const int wid = tid >> 6, lane = tid & 63;
  const int l15 = lane & 15, kq = lane >> 4;
  const int flat = blockIdx.y * gridDim.x + blockIdx.x;   // 1024 blocks
  const int swz = (flat & 7) * 128 + (flat >> 3);         // bijective XCD chunking
  const int bh = swz >> 5, b = bh >> 4, h = bh & 15;
  const int q0 = (swz & 31) * 64;

  const ushort_t* kp[2];
  const ushort_t* vp[2];
#pragma unroll
  for (int rr = 0; rr < 2; ++rr) {
    int c = rr * 256 + tid;
    int krow = c >> 4, kc = (c & 15) ^ (krow & 15);       // 16 chunks/row (128 d)
    kp[rr] = K + (size_t)(b * T_ + krow) * D_ + h * HD_ + kc * 8;
    int drow = c >> 2, vc = (c & 3) ^ ((drow >> 1) & 3);  // 4 chunks/row (32 keys)
    vp[rr] = Vt + ((size_t)bh * HD_ + drow) * T_ + vc * 8;
  }

  // Q A-frags: wave owns 16 q-rows (q0 + wid*16 + l15); scale pre-folded
  bf16x8 qa[4];
  {
    const ushort_t* qp = Q + (size_t)(b * T_ + q0 + wid * 16 + l15) * D_ + h * HD_ + kq * 8;
#pragma unroll
    for (int kk = 0; kk < 4; ++kk) qa[kk] = *(const bf16x8*)(qp + kk * 32);
  }

  f32x4 o[8];
#pragma unroll
  for (int dt = 0; dt < 8; ++dt) o[dt] = (f32x4){0.f, 0.f, 0.f, 0.f};
  float l[4] = {0.f, 0.f, 0.f, 0.f};

  // prologue: stage K(0) and V(0) into buf 0
#pragma unroll
  for (int rr = 0; rr < 2; ++rr)
    async16(kp[rr], &Ks[0][(rr * 256 + wid * 64) * 8]);
#pragma unroll
  for (int rr = 0; rr < 2; ++rr)
    async16(vp[rr], &Vs[0][(rr * 256 + wid * 64) * 8]);

  for (int kt = 0; kt < 64; ++kt) {
    const int buf = kt & 1;
    // my stages of [buf] (issued last iter / prologue) done; barrier -> everyone's done.
    // Also orders: no wave writes [buf^1] (below) before all finished reading it (prev iter).
    __asm__ volatile("s_waitcnt vmcnt(0)" ::: "memory");
    __builtin_amdgcn_s_barrier();

    if (kt + 1 < 64) {
#pragma unroll
      for (int rr = 0; rr < 2; ++rr)
        async16(kp[rr] + (size_t)(kt + 1) * 32 * D_, &Ks[buf ^ 1][(rr * 256 + wid * 64) * 8]);
#pragma unroll
      for (int rr = 0; rr < 2; ++rr)
        async16(vp[rr] + (size_t)(kt + 1) * 32, &Vs[buf ^ 1][(rr * 256 + wid * 64) * 8]);
    }

    // S = Q*K^T: rows = 16 q, cols = 32 keys (j*16+l15)
    f32x4 s[2];
    s[0] = (f32x4){0.f, 0.f, 0.f, 0.f};
    s[1] = (f32x4){0.f, 0.f, 0.f, 0.f};
    __builtin_amdgcn_s_setprio(1);
#pragma unroll
    for (int j = 0; j < 2; ++j) {
#pragma unroll
      for (int kk = 0; kk < 4; ++kk) {
        int row = j * 16 + l15;
        bf16x8 kf = *(const bf16x8*)&Ks[buf][row * 128 + ((kk * 4 + kq) ^ l15) * 8];
        s[j] = __builtin_amdgcn_mfma_f32_16x16x32_bf16(qa[kk], kf, s[j], 0, 0, 0);
      }
    }
    __builtin_amdgcn_s_setprio(0);

    // fixed-max softmax (exp2 domain), per-lane partials, swizzled P store
#pragma unroll
    for (int r = 0; r < 4; ++r) {
      const int row = kq * 4 + r;              // q-row 0..15
      const int sw = (row >> 1) & 3;
#pragma unroll
      for (int j = 0; j < 2; ++j) {
        float p = __builtin_amdgcn_exp2f(s[j][r]);
        l[r] += p;
        int c = j * 2 + (l15 >> 3);            // key chunk 0..3
        Ps[wid][row * 32 + ((c ^ sw) & 3) * 8 + (l15 & 7)] = (short)f2bf(p);
      }
    }
    __asm__ volatile("s_waitcnt lgkmcnt(0)" ::: "memory");   // P writes -> cross-lane reads

    // P A-frag: rows l15, keys chunk kq (stored at kq ^ sw(l15))
    bf16x8 pf = *(const bf16x8*)&Ps[wid][l15 * 32 + (kq ^ ((l15 >> 1) & 3)) * 8];

    // O += P * V (Vs[buf] was staged last iteration; no wait needed)
    __builtin_amdgcn_s_setprio(1);
#pragma unroll
    for (int dt = 0; dt < 8; ++dt) {
      bf16x8 vf = *(const bf16x8*)&Vs[buf][(dt * 16 + l15) * 32 + (kq ^ ((l15 >> 1) & 3)) * 8];
      o[dt] = __builtin_amdgcn_mfma_f32_16x16x32_bf16(pf, vf, o[dt], 0, 0, 0);
    }
    __builtin_amdgcn_s_setprio(0);
  }

  // denominators: keys live across l15 (16 lanes) for fixed kq
#pragma unroll
  for (int r = 0; r < 4; ++r) {
#pragma unroll
    for (int off = 1; off < 16; off <<= 1) l[r] += __shfl_xor(l[r], off, 64);
  }
#pragma unroll
  for (int r = 0; r < 4; ++r) {
    float inv = 1.f / l[r];
#pragma unroll
    for (int dt = 0; dt < 8; ++dt) {
      size_t idx = (size_t)(b * T_ + q0 + wid * 16 + kq * 4 + r) * D_ + h * HD_ + dt * 16 + l15;
      O[idx] = f2bf(o[dt][r] * inv);
    }
  }
}

// ---------------- launch ----------------
extern "C" void kernel_launch(void* const* d_in, const int* in_sizes, int n_in,
                              void* d_out, int out_size, void* d_ws, size_t ws_size,
                              hipStream_t stream) {
  const float* x  = (const float*)d_in[0];
  const float* cs = (const float*)d_in[1];
  const float* sn = (const float*)d_in[2];
  const float* wq = (const float*)d_in[3];
  const float* bq = (const float*)d_in[4];
  const float* wk = (const float*)d_in[5];
  const float* bk = (const float*)d_in[6];
  const float* wv = (const float*)d_in[7];
  const float* bv = (const float*)d_in[8];
  const float* gq = (const float*)d_in[9];
  const float* gk = (const float*)d_in[10];
  const float* wo = (const float*)d_in[11];
  const float* bo = (const float*)d_in[12];
  const float* wg = (const float*)d_in[13];
  const float* bg = (const float*)d_in[14];

  char* ws = (char*)d_ws;
  const size_t SZ_BTD_BF = (size_t)BT_ * D_ * 2;   // 16 MB
  const size_t SZ_DD_BF  = (size_t)D_ * D_ * 2;    //  8 MB
  const size_t SZ_BTD_F  = (size_t)BT_ * D_ * 4;   // 32 MB

  size_t off = 0;
  ushort_t* xb  = (ushort_t*)(ws + off); off += SZ_BTD_BF;        // aliased as attn later
  ushort_t* wqT = (ushort_t*)(ws + off); off += SZ_DD_BF;
  ushort_t* wkT = (ushort_t*)(ws + off); off += SZ_DD_BF;
  ushort_t* wvT = (ushort_t*)(ws + off); off += SZ_DD_BF;
  ushort_t* woT = (ushort_t*)(ws + off); off += SZ_DD_BF;
  ushort_t* wgT = (ushort_t*)(ws + off); off += SZ_DD_BF;
  float*    qf  = (float*)(ws + off);    off += SZ_BTD_F;         // aliased as outf later
  float*    kf  = (float*)(ws + off);    off += SZ_BTD_F;         // aliased as outb later
  ushort_t* vb  = (ushort_t*)(ws + off); off += SZ_BTD_BF;
  ushort_t* qb  = (ushort_t*)(ws + off); off += SZ_BTD_BF;
  ushort_t* kb  = (ushort_t*)(ws + off); off += SZ_BTD_BF;
  ushort_t* vt  = (ushort_t*)(ws + off); off += SZ_BTD_BF;        // ~193 MB total
  ushort_t* attn = xb;            // xb dead after QKV GEMMs
  float*    outf = qf;            // qf dead after norm_rope(q)
  ushort_t* outb = (ushort_t*)kf; // kf dead after norm_rope(k)

  const float cl2 = 0.08838834764831845f * 1.4426950408889634f;  // 1/sqrt(128)*log2e

  k_cast_x<<<8192, 256, 0, stream>>>(x, xb);
  k_twT5<<<dim3(64, 64, 5), dim3(32, 8), 0, stream>>>(wq, wk, wv, wo, wg,
                                                      wqT, wkT, wvT, woT, wgT);

  k_gemm<0><<<dim3(16, 32), 256, 0, stream>>>(xb, wqT, bq, qf, nullptr, nullptr);
  k_gemm<0><<<dim3(16, 32), 256, 0, stream>>>(xb, wkT, bk, kf, nullptr, nullptr);
  k_gemm<1><<<dim3(16, 32), 256, 0, stream>>>(xb, wvT, bv, nullptr, vb, nullptr);

  k_normrope<<<4096, 256, 0, stream>>>(qf, gq, cs, sn, qb, cl2);
  k_normrope<<<4096, 256, 0, stream>>>(kf, gk, cs, sn, kb, 1.0f);
  k_tv<<<dim3(4, 64, 32), dim3(32, 8), 0, stream>>>(vb, vt);

  k_flash<<<dim3(32, 32), 256, 0, stream>>>(qb, kb, vt, attn);

  k_gemm<2><<<dim3(16, 32), 256, 0, stream>>>(attn, woT, bo, outf, outb, nullptr);
  k_gemm<3><<<dim3(16, 32), 256, 0, stream>>>(outb, wgT, bg, (float*)d_out, nullptr, outf);
}

// Round 6
// 503.025 us; speedup vs baseline: 1.2036x; 1.0417x over previous
//
#include <hip/hip_runtime.h>
#include <stdint.h>

typedef unsigned short ushort_t;
typedef __attribute__((ext_vector_type(8))) short bf16x8;
typedef __attribute__((ext_vector_type(4))) float f32x4;
typedef __attribute__((ext_vector_type(4))) unsigned short u16x4;
typedef __attribute__((ext_vector_type(2))) unsigned int u32x2;

#define B_ 2
#define T_ 2048
#define D_ 2048
#define H_ 16
#define HD_ 128
#define BT_ 4096

__device__ __forceinline__ ushort_t f2bf(float f) {
  unsigned u = __float_as_uint(f);
  u += 0x7FFFu + ((u >> 16) & 1u);   // RNE
  return (ushort_t)(u >> 16);
}

// pack two f32 -> u32 of 2 bf16 (RNE), low = first arg [T12 primitive, m214v22]
__device__ __forceinline__ unsigned cvtpk(float lo, float hi) {
  unsigned r;
  asm("v_cvt_pk_bf16_f32 %0, %1, %2" : "=v"(r) : "v"(lo), "v"(hi));
  return r;
}

__device__ __forceinline__ void async16(const void* g, void* l) {
  __builtin_amdgcn_global_load_lds(
      (const __attribute__((address_space(1))) unsigned int*)g,
      (__attribute__((address_space(3))) unsigned int*)l, 16, 0, 0);
}

// ---------------- elementwise cast x -> bf16 ----------------
__global__ void k_cast_x(const float* __restrict__ in, ushort_t* __restrict__ out) {
  int i = blockIdx.x * 256 + threadIdx.x;          // 4 elements per thread
  float4 v = ((const float4*)in)[i];
  u16x4 r = { f2bf(v.x), f2bf(v.y), f2bf(v.z), f2bf(v.w) };
  ((u16x4*)out)[i] = r;
}

// ---------------- fused weight transpose+cast x5: w[K][N] f32 -> wt[N][K] bf16 ----------------
__global__ void k_twT5(const float* __restrict__ wa, const float* __restrict__ wb,
                       const float* __restrict__ wc, const float* __restrict__ wd,
                       const float* __restrict__ we,
                       ushort_t* __restrict__ ta, ushort_t* __restrict__ tb,
                       ushort_t* __restrict__ tc, ushort_t* __restrict__ td,
                       ushort_t* __restrict__ te) {
  const float* w; ushort_t* wt;
  switch (blockIdx.z) {
    case 0: w = wa; wt = ta; break;
    case 1: w = wb; wt = tb; break;
    case 2: w = wc; wt = tc; break;
    case 3: w = wd; wt = td; break;
    default: w = we; wt = te; break;
  }
  __shared__ float tile[32][33];
  int tx = threadIdx.x, ty = threadIdx.y;
  int x = blockIdx.x * 32 + tx;        // N index
  int y0 = blockIdx.y * 32;            // K index
#pragma unroll
  for (int k = 0; k < 4; ++k)
    tile[ty + k * 8][tx] = w[(size_t)(y0 + ty + k * 8) * D_ + x];
  __syncthreads();
  int ox = blockIdx.y * 32 + tx;       // K contiguous on write
  int oy0 = blockIdx.x * 32;           // N
#pragma unroll
  for (int k = 0; k < 4; ++k)
    wt[(size_t)(oy0 + ty + k * 8) * D_ + ox] = f2bf(tile[tx][ty + k * 8]);
}

// ---------------- GEMM: C[M=4096][N=2048] = A(bf16 MxK) * Bt(bf16 NxK)^T + bias ----------------
// 512 threads / 8 waves per block (each wave owns 64x32), 128x128 tile, BK=64,
// double-buffered, ONE vmcnt(0)+barrier per K-step. Grid 512 = 2 blocks/CU ->
// 16 waves/CU = 4 waves/SIMD (was 2): occupancy lever, same as flash round-4 fix.
// EPI 0: fp32. 1: bf16. 2: both. 3: gate (out = aux*sigmoid(val))
template <int EPI>
__global__ __launch_bounds__(512) void k_gemm(
    const ushort_t* __restrict__ A, const ushort_t* __restrict__ Bt,
    const float* __restrict__ bias, float* __restrict__ outF,
    ushort_t* __restrict__ outB, const float* __restrict__ aux) {
  __shared__ __align__(16) short As[2][128 * 64];
  __shared__ __align__(16) short Bs[2][128 * 64];
  const int tid = threadIdx.x;
  const int wid = tid >> 6, lane = tid & 63;
  const int l15 = lane & 15, kq = lane >> 4;
  const int m0 = (wid >> 2) * 64, n0 = (wid & 3) * 32;
  const int tileM = blockIdx.y * 128, tileN = blockIdx.x * 128;

  f32x4 acc[4][2];
#pragma unroll
  for (int i = 0; i < 4; ++i)
#pragma unroll
    for (int j = 0; j < 2; ++j) acc[i][j] = (f32x4){0.f, 0.f, 0.f, 0.f};

  auto stage = [&](int sbuf, int k0) {
#pragma unroll
    for (int rr = 0; rr < 2; ++rr) {
      int c = rr * 512 + tid;          // 1024 chunks of 16B per matrix
      int row = c >> 3, p = c & 7;
      int gc = p ^ (row & 7);          // XOR-swizzled global chunk (bank-conflict fix)
      async16(A + (size_t)(tileM + row) * D_ + k0 + gc * 8,
              &As[sbuf][(rr * 512 + wid * 64) * 8]);
      async16(Bt + (size_t)(tileN + row) * D_ + k0 + gc * 8,
              &Bs[sbuf][(rr * 512 + wid * 64) * 8]);
    }
  };

  stage(0, 0);
  for (int k0 = 0; k0 < D_; k0 += 64) {
    const int buf = (k0 >> 6) & 1;
    // my stage of [buf] (issued last iter) done; barrier -> everyone's done.
    __asm__ volatile("s_waitcnt vmcnt(0)" ::: "memory");
    __builtin_amdgcn_s_barrier();
    if (k0 + 64 < D_) stage(buf ^ 1, k0 + 64);   // lands during compute below
#pragma unroll
    for (int half = 0; half < 2; ++half) {
      bf16x8 a[4], b[2];
#pragma unroll
      for (int i = 0; i < 4; ++i) {
        int row = m0 + i * 16 + l15;
        a[i] = *(const bf16x8*)&As[buf][row * 64 + ((half * 4 + kq) ^ (row & 7)) * 8];
      }
#pragma unroll
      for (int j = 0; j < 2; ++j) {
        int row = n0 + j * 16 + l15;
        b[j] = *(const bf16x8*)&Bs[buf][row * 64 + ((half * 4 + kq) ^ (row & 7)) * 8];
      }
#pragma unroll
      for (int i = 0; i < 4; ++i)
#pragma unroll
        for (int j = 0; j < 2; ++j)
          acc[i][j] = __builtin_amdgcn_mfma_f32_16x16x32_bf16(a[i], b[j], acc[i][j], 0, 0, 0);
    }
  }

#pragma unroll
  for (int i = 0; i < 4; ++i) {
#pragma unroll
    for (int j = 0; j < 2; ++j) {
#pragma unroll
      for (int r = 0; r < 4; ++r) {
        int gm = tileM + m0 + i * 16 + kq * 4 + r;   // C/D: row = quad*4 + reg
        int gn = tileN + n0 + j * 16 + l15;          //      col = lane&15
        size_t idx = (size_t)gm * D_ + gn;
        float val = acc[i][j][r] + bias[gn];
        if (EPI == 0) {
          outF[idx] = val;
        } else if (EPI == 1) {
          outB[idx] = f2bf(val);
        } else if (EPI == 2) {
          outF[idx] = val; outB[idx] = f2bf(val);
        } else {
          float sg = 1.f / (1.f + __expf(-val));
          outF[idx] = aux[idx] * sg;
        }
      }
    }
  }
}

// ---------------- fused RMSNorm (full D) + RoPE, fp32 in -> bf16 out (x oscale) ----------------
__global__ void k_normrope(const float* __restrict__ in, const float* __restrict__ g,
                           const float* __restrict__ cs, const float* __restrict__ sn,
                           ushort_t* __restrict__ out, float oscale) {
  const int row = blockIdx.x;            // 0..4095 = b*T + t
  const int t = row & (T_ - 1);
  const float* x = in + (size_t)row * D_;
  const int tid = threadIdx.x;
  float ss = 0.f;
#pragma unroll
  for (int i = tid; i < 512; i += 256) {
    float4 v = ((const float4*)x)[i];
    ss += v.x * v.x + v.y * v.y + v.z * v.z + v.w * v.w;
  }
#pragma unroll
  for (int off = 1; off < 64; off <<= 1) ss += __shfl_xor(ss, off, 64);
  __shared__ float part[4];
  if ((tid & 63) == 0) part[tid >> 6] = ss;
  __syncthreads();
  float rstd = rsqrtf((part[0] + part[1] + part[2] + part[3]) * (1.f / (float)D_) + 1e-6f);
  rstd *= oscale;                        // fold attention scale*log2e into Q
#pragma unroll
  for (int p = tid; p < 1024; p += 256) {
    int head = p >> 6, i = p & 63;
    int e1 = head * HD_ + i, e2 = e1 + 64;
    float x1 = x[e1] * rstd * g[e1];
    float x2 = x[e2] * rstd * g[e2];
    float c = cs[t * 64 + i], s = sn[t * 64 + i];
    out[(size_t)row * D_ + e1] = f2bf(x1 * c - s * x2);
    out[(size_t)row * D_ + e2] = f2bf(x2 * c + s * x1);
  }
}

// ---------------- V transpose per head: v[b][t][h*128+d] -> vt[bh][d][t] ----------------
__global__ void k_tv(const ushort_t* __restrict__ v, ushort_t* __restrict__ vt) {
  __shared__ ushort_t tile[32][33];
  int bh = blockIdx.z, b = bh >> 4, h = bh & 15;
  int tx = threadIdx.x, ty = threadIdx.y;
  int d = blockIdx.x * 32 + tx;
  int t0 = blockIdx.y * 32;
#pragma unroll
  for (int k = 0; k < 4; ++k)
    tile[ty + k * 8][tx] = v[(size_t)(b * T_ + t0 + ty + k * 8) * D_ + h * HD_ + d];
  __syncthreads();
  int ot = t0 + tx;
  int od0 = blockIdx.x * 32;
#pragma unroll
  for (int k = 0; k < 4; ++k)
    vt[((size_t)bh * HD_ + od0 + ty + k * 8) * T_ + ot] = tile[tx][ty + k * 8];
}

// ---------------- flash v8: swapped QK (A=K, B=Q) -> lane owns q=l15 with 4
// CONSECUTIVE keys per j: denominator is a lane-local scalar; P packed with
// cvt_pk (4 insts) + 2 ds_write_b64 (was 8 f2bf + 8 ds_write_u16). PV keeps the
// single ds_read_b128 via 16B-granular XOR swizzle c4^=(q>>1)&3 (write 2-way,
// read 2-way = free). K/V double-buffered, one vmcnt(0)+barrier per iter. ----------------
__global__ __launch_bounds__(256) void k_flash(
    const ushort_t* __restrict__ Q, const ushort_t* __restrict__ K,
    const ushort_t* __restrict__ Vt, ushort_t* __restrict__ O) {
  __shared__ __align__(16) short Ks[2][32 * 128];   // [buf][key][d]   8 KB each
  __shared__ __align__(16) short Vs[2][128 * 32];   // [buf][d][key]   8 KB each
  __shared__ __align__(16) short Ps[4][16 * 32];    // per-wave P[q][key], swizzled 16B chunks

  const int tid = threadIdx.x;
  const int wid = tid >> 6, lane = tid & 63;
  const int l15 = lane & 15, kq = lane >> 4;
  const int flat = blockIdx.y * gridDim.x + blockIdx.x;   // 1024 blocks
  const int swz = (flat & 7) * 128 + (flat >> 3);         // bijective XCD chunking
  const int bh = swz >> 5, b = bh >> 4, h = bh & 15;
  const int q0 = (swz & 31) * 64;

  const ushort_t* kp[2];
  const ushort_t* vp[2];
#pragma unroll
  for (int rr = 0; rr < 2; ++rr) {
    int c = rr * 256 + tid;
    int krow = c >> 4, kc = (c & 15) ^ (krow & 15);       // 16 chunks/row (128 d)
    kp[rr] = K + (size_t)(b * T_ + krow) * D_ + h * HD_ + kc * 8;
    int drow = c >> 2, vc = (c & 3) ^ ((drow >> 1) & 3);  // 4 chunks/row (32 keys)
    vp[rr] = Vt + ((size_t)bh * HD_ + drow) * T_ + vc * 8;
  }

  // Q B-frags: wave owns 16 q-rows (q0 + wid*16 + l15); scale pre-folded
  bf16x8 qa[4];
  {
    const ushort_t* qp = Q + (size_t)(b * T_ + q0 + wid * 16 + l15) * D_ + h * HD_ + kq * 8;
#pragma unroll
    for (int kk = 0; kk < 4; ++kk) qa[kk] = *(const bf16x8*)(qp + kk * 32);
  }

  // hoisted P-store / P-read addresses (iteration-invariant)
  char* const ps_base = (char*)&Ps[wid][0];
  char* const pw0 = ps_base + l15 * 64 + (((kq >> 1) ^ ((l15 >> 1) & 3)) * 16) + (kq & 1) * 8;       // j=0
  char* const pw1 = ps_base + l15 * 64 + (((2 + (kq >> 1)) ^ ((l15 >> 1) & 3)) * 16) + (kq & 1) * 8; // j=1
  const char* const prd = ps_base + l15 * 64 + ((kq ^ ((l15 >> 1) & 3)) * 16);

  f32x4 o[8];
#pragma unroll
  for (int dt = 0; dt < 8; ++dt) o[dt] = (f32x4){0.f, 0.f, 0.f, 0.f};
  float lsum = 0.f;                      // denominator for q = l15 (lane-local)

  // prologue: stage K(0) and V(0) into buf 0
#pragma unroll
  for (int rr = 0; rr < 2; ++rr)
    async16(kp[rr], &Ks[0][(rr * 256 + wid * 64) * 8]);
#pragma unroll
  for (int rr = 0; rr < 2; ++rr)
    async16(vp[rr], &Vs[0][(rr * 256 + wid * 64) * 8]);

  for (int kt = 0; kt < 64; ++kt) {
    const int buf = kt & 1;
    // my stages of [buf] (issued last iter / prologue) done; barrier -> everyone's done.
    __asm__ volatile("s_waitcnt vmcnt(0)" ::: "memory");
    __builtin_amdgcn_s_barrier();

    if (kt + 1 < 64) {
#pragma unroll
      for (int rr = 0; rr < 2; ++rr)
        async16(kp[rr] + (size_t)(kt + 1) * 32 * D_, &Ks[buf ^ 1][(rr * 256 + wid * 64) * 8]);
#pragma unroll
      for (int rr = 0; rr < 2; ++rr)
        async16(vp[rr] + (size_t)(kt + 1) * 32, &Vs[buf ^ 1][(rr * 256 + wid * 64) * 8]);
    }

    // S^T tile: A = K rows (keys), B = Q rows -> D: row = key(within16) = kq*4+r,
    // col = q = l15. Per lane: q=l15, keys j*16 + kq*4 + {0..3}.
    f32x4 s[2];
    s[0] = (f32x4){0.f, 0.f, 0.f, 0.f};
    s[1] = (f32x4){0.f, 0.f, 0.f, 0.f};
    __builtin_amdgcn_s_setprio(1);
#pragma unroll
    for (int j = 0; j < 2; ++j) {
#pragma unroll
      for (int kk = 0; kk < 4; ++kk) {
        int row = j * 16 + l15;
        bf16x8 kf = *(const bf16x8*)&Ks[buf][row * 128 + ((kk * 4 + kq) ^ l15) * 8];
        s[j] = __builtin_amdgcn_mfma_f32_16x16x32_bf16(kf, qa[kk], s[j], 0, 0, 0);
      }
    }
    __builtin_amdgcn_s_setprio(0);

    // fixed-max softmax (exp2 domain): lane-local sum + packed b64 P store
#pragma unroll
    for (int j = 0; j < 2; ++j) {
      float p0 = __builtin_amdgcn_exp2f(s[j][0]);
      float p1 = __builtin_amdgcn_exp2f(s[j][1]);
      float p2 = __builtin_amdgcn_exp2f(s[j][2]);
      float p3 = __builtin_amdgcn_exp2f(s[j][3]);
      lsum += (p0 + p1) + (p2 + p3);
      u32x2 w;
      w.x = cvtpk(p0, p1);               // keys kq*4+0, +1 (low u16 first)
      w.y = cvtpk(p2, p3);               // keys kq*4+2, +3
      *(u32x2*)(j == 0 ? pw0 : pw1) = w;
    }
    __asm__ volatile("s_waitcnt lgkmcnt(0)" ::: "memory");   // P writes -> cross-lane reads

    // P A-frag: rows q = l15, keys kq*8..kq*8+7 (one b128, swizzled chunk)
    bf16x8 pf = *(const bf16x8*)prd;

    // O += P * V (Vs[buf] staged last iteration; covered by top-of-iter drain)
    __builtin_amdgcn_s_setprio(1);
#pragma unroll
    for (int dt = 0; dt < 8; ++dt) {
      bf16x8 vf = *(const bf16x8*)&Vs[buf][(dt * 16 + l15) * 32 + (kq ^ ((l15 >> 1) & 3)) * 8];
      o[dt] = __builtin_amdgcn_mfma_f32_16x16x32_bf16(pf, vf, o[dt], 0, 0, 0);
    }
    __builtin_amdgcn_s_setprio(0);
  }

  // denominator: lane holds partial for q=l15 over keys {kq*4+r, 16+kq*4+r} of every
  // tile; reduce across the 4 kq groups (lane^16, lane^32), then fetch for q=kq*4+r.
  lsum += __shfl_xor(lsum, 16, 64);
  lsum += __shfl_xor(lsum, 32, 64);
#pragma unroll
  for (int r = 0; r < 4; ++r) {
    float inv = 1.f / __shfl(lsum, kq * 4 + r, 64);
#pragma unroll
    for (int dt = 0; dt < 8; ++dt) {
      size_t idx = (size_t)(b * T_ + q0 + wid * 16 + kq * 4 + r) * D_ + h * HD_ + dt * 16 + l15;
      O[idx] = f2bf(o[dt][r] * inv);
    }
  }
}

// ---------------- launch ----------------
extern "C" void kernel_launch(void* const* d_in, const int* in_sizes, int n_in,
                              void* d_out, int out_size, void* d_ws, size_t ws_size,
                              hipStream_t stream) {
  const float* x  = (const float*)d_in[0];
  const float* cs = (const float*)d_in[1];
  const float* sn = (const float*)d_in[2];
  const float* wq = (const float*)d_in[3];
  const float* bq = (const float*)d_in[4];
  const float* wk = (const float*)d_in[5];
  const float* bk = (const float*)d_in[6];
  const float* wv = (const float*)d_in[7];
  const float* bv = (const float*)d_in[8];
  const float* gq = (const float*)d_in[9];
  const float* gk = (const float*)d_in[10];
  const float* wo = (const float*)d_in[11];
  const float* bo = (const float*)d_in[12];
  const float* wg = (const float*)d_in[13];
  const float* bg = (const float*)d_in[14];

  char* ws = (char*)d_ws;
  const size_t SZ_BTD_BF = (size_t)BT_ * D_ * 2;   // 16 MB
  const size_t SZ_DD_BF  = (size_t)D_ * D_ * 2;    //  8 MB
  const size_t SZ_BTD_F  = (size_t)BT_ * D_ * 4;   // 32 MB

  size_t off = 0;
  ushort_t* xb  = (ushort_t*)(ws + off); off += SZ_BTD_BF;        // aliased as attn later
  ushort_t* wqT = (ushort_t*)(ws + off); off += SZ_DD_BF;
  ushort_t* wkT = (ushort_t*)(ws + off); off += SZ_DD_BF;
  ushort_t* wvT = (ushort_t*)(ws + off); off += SZ_DD_BF;
  ushort_t* woT = (ushort_t*)(ws + off); off += SZ_DD_BF;
  ushort_t* wgT = (ushort_t*)(ws + off); off += SZ_DD_BF;
  float*    qf  = (float*)(ws + off);    off += SZ_BTD_F;         // aliased as outf later
  float*    kf  = (float*)(ws + off);    off += SZ_BTD_F;         // aliased as outb later
  ushort_t* vb  = (ushort_t*)(ws + off); off += SZ_BTD_BF;
  ushort_t* qb  = (ushort_t*)(ws + off); off += SZ_BTD_BF;
  ushort_t* kb  = (ushort_t*)(ws + off); off += SZ_BTD_BF;
  ushort_t* vt  = (ushort_t*)(ws + off); off += SZ_BTD_BF;        // ~193 MB total
  ushort_t* attn = xb;            // xb dead after QKV GEMMs
  float*    outf = qf;            // qf dead after norm_rope(q)
  ushort_t* outb = (ushort_t*)kf; // kf dead after norm_rope(k)

  const float cl2 = 0.08838834764831845f * 1.4426950408889634f;  // 1/sqrt(128)*log2e

  k_cast_x<<<8192, 256, 0, stream>>>(x, xb);
  k_twT5<<<dim3(64, 64, 5), dim3(32, 8), 0, stream>>>(wq, wk, wv, wo, wg,
                                                      wqT, wkT, wvT, woT, wgT);

  k_gemm<0><<<dim3(16, 32), 512, 0, stream>>>(xb, wqT, bq, qf, nullptr, nullptr);
  k_gemm<0><<<dim3(16, 32), 512, 0, stream>>>(xb, wkT, bk, kf, nullptr, nullptr);
  k_gemm<1><<<dim3(16, 32), 512, 0, stream>>>(xb, wvT, bv, nullptr, vb, nullptr);

  k_normrope<<<4096, 256, 0, stream>>>(qf, gq, cs, sn, qb, cl2);
  k_normrope<<<4096, 256, 0, stream>>>(kf, gk, cs, sn, kb, 1.0f);
  k_tv<<<dim3(4, 64, 32), dim3(32, 8), 0, stream>>>(vb, vt);

  k_flash<<<dim3(32, 32), 256, 0, stream>>>(qb, kb, vt, attn);

  k_gemm<2><<<dim3(16, 32), 512, 0, stream>>>(attn, woT, bo, outf, outb, nullptr);
  k_gemm<3><<<dim3(16, 32), 512, 0, stream>>>(outb, wgT, bg, (float*)d_out, nullptr, outf);
}

// Round 7
// 500.558 us; speedup vs baseline: 1.2096x; 1.0049x over previous
//
#include <hip/hip_runtime.h>
#include <stdint.h>

typedef unsigned short ushort_t;
typedef __attribute__((ext_vector_type(8))) short bf16x8;
typedef __attribute__((ext_vector_type(4))) float f32x4;
typedef __attribute__((ext_vector_type(16))) float f32x16;
typedef __attribute__((ext_vector_type(4))) unsigned short u16x4;
typedef __attribute__((ext_vector_type(2))) unsigned int u32x2;

#define B_ 2
#define T_ 2048
#define D_ 2048
#define H_ 16
#define HD_ 128
#define BT_ 4096

__device__ __forceinline__ ushort_t f2bf(float f) {
  unsigned u = __float_as_uint(f);
  u += 0x7FFFu + ((u >> 16) & 1u);   // RNE
  return (ushort_t)(u >> 16);
}

// pack two f32 -> u32 of 2 bf16 (RNE), low = first arg [T12 primitive, m214v22]
__device__ __forceinline__ unsigned cvtpk(float lo, float hi) {
  unsigned r;
  asm("v_cvt_pk_bf16_f32 %0, %1, %2" : "=v"(r) : "v"(lo), "v"(hi));
  return r;
}

__device__ __forceinline__ bf16x8 mk8(unsigned a, unsigned b, unsigned c, unsigned d) {
  union { unsigned u[4]; bf16x8 v; } x;
  x.u[0] = a; x.u[1] = b; x.u[2] = c; x.u[3] = d;
  return x.v;
}

__device__ __forceinline__ void async16(const void* g, void* l) {
  __builtin_amdgcn_global_load_lds(
      (const __attribute__((address_space(1))) unsigned int*)g,
      (__attribute__((address_space(3))) unsigned int*)l, 16, 0, 0);
}

// ---------------- elementwise cast x -> bf16 ----------------
__global__ void k_cast_x(const float* __restrict__ in, ushort_t* __restrict__ out) {
  int i = blockIdx.x * 256 + threadIdx.x;          // 4 elements per thread
  float4 v = ((const float4*)in)[i];
  u16x4 r = { f2bf(v.x), f2bf(v.y), f2bf(v.z), f2bf(v.w) };
  ((u16x4*)out)[i] = r;
}

// ---------------- fused weight transpose+cast x5: w[K][N] f32 -> wt[N][K] bf16 ----------------
__global__ void k_twT5(const float* __restrict__ wa, const float* __restrict__ wb,
                       const float* __restrict__ wc, const float* __restrict__ wd,
                       const float* __restrict__ we,
                       ushort_t* __restrict__ ta, ushort_t* __restrict__ tb,
                       ushort_t* __restrict__ tc, ushort_t* __restrict__ td,
                       ushort_t* __restrict__ te) {
  const float* w; ushort_t* wt;
  switch (blockIdx.z) {
    case 0: w = wa; wt = ta; break;
    case 1: w = wb; wt = tb; break;
    case 2: w = wc; wt = tc; break;
    case 3: w = wd; wt = td; break;
    default: w = we; wt = te; break;
  }
  __shared__ float tile[32][33];
  int tx = threadIdx.x, ty = threadIdx.y;
  int x = blockIdx.x * 32 + tx;        // N index
  int y0 = blockIdx.y * 32;            // K index
#pragma unroll
  for (int k = 0; k < 4; ++k)
    tile[ty + k * 8][tx] = w[(size_t)(y0 + ty + k * 8) * D_ + x];
  __syncthreads();
  int ox = blockIdx.y * 32 + tx;       // K contiguous on write
  int oy0 = blockIdx.x * 32;           // N
#pragma unroll
  for (int k = 0; k < 4; ++k)
    wt[(size_t)(oy0 + ty + k * 8) * D_ + ox] = f2bf(tile[tx][ty + k * 8]);
}

// ---------------- GEMM: C[M=4096][N=2048] = A(bf16 MxK) * Bt(bf16 NxK)^T + bias ----------------
// 512 threads / 8 waves (each 64x32), 128x128 tile, BK=64, dbuf, one barrier per K-step.
// EPI 0: fp32. 1: bf16. 2: both. 3: gate (out = aux*sigmoid(val))
template <int EPI>
__global__ __launch_bounds__(512) void k_gemm(
    const ushort_t* __restrict__ A, const ushort_t* __restrict__ Bt,
    const float* __restrict__ bias, float* __restrict__ outF,
    ushort_t* __restrict__ outB, const float* __restrict__ aux) {
  __shared__ __align__(16) short As[2][128 * 64];
  __shared__ __align__(16) short Bs[2][128 * 64];
  const int tid = threadIdx.x;
  const int wid = tid >> 6, lane = tid & 63;
  const int l15 = lane & 15, kq = lane >> 4;
  const int m0 = (wid >> 2) * 64, n0 = (wid & 3) * 32;
  const int tileM = blockIdx.y * 128, tileN = blockIdx.x * 128;

  f32x4 acc[4][2];
#pragma unroll
  for (int i = 0; i < 4; ++i)
#pragma unroll
    for (int j = 0; j < 2; ++j) acc[i][j] = (f32x4){0.f, 0.f, 0.f, 0.f};

  auto stage = [&](int sbuf, int k0) {
#pragma unroll
    for (int rr = 0; rr < 2; ++rr) {
      int c = rr * 512 + tid;          // 1024 chunks of 16B per matrix
      int row = c >> 3, p = c & 7;
      int gc = p ^ (row & 7);          // XOR-swizzled global chunk (bank-conflict fix)
      async16(A + (size_t)(tileM + row) * D_ + k0 + gc * 8,
              &As[sbuf][(rr * 512 + wid * 64) * 8]);
      async16(Bt + (size_t)(tileN + row) * D_ + k0 + gc * 8,
              &Bs[sbuf][(rr * 512 + wid * 64) * 8]);
    }
  };

  stage(0, 0);
  for (int k0 = 0; k0 < D_; k0 += 64) {
    const int buf = (k0 >> 6) & 1;
    __asm__ volatile("s_waitcnt vmcnt(0)" ::: "memory");
    __builtin_amdgcn_s_barrier();
    if (k0 + 64 < D_) stage(buf ^ 1, k0 + 64);   // lands during compute below
#pragma unroll
    for (int half = 0; half < 2; ++half) {
      bf16x8 a[4], b[2];
#pragma unroll
      for (int i = 0; i < 4; ++i) {
        int row = m0 + i * 16 + l15;
        a[i] = *(const bf16x8*)&As[buf][row * 64 + ((half * 4 + kq) ^ (row & 7)) * 8];
      }
#pragma unroll
      for (int j = 0; j < 2; ++j) {
        int row = n0 + j * 16 + l15;
        b[j] = *(const bf16x8*)&Bs[buf][row * 64 + ((half * 4 + kq) ^ (row & 7)) * 8];
      }
#pragma unroll
      for (int i = 0; i < 4; ++i)
#pragma unroll
        for (int j = 0; j < 2; ++j)
          acc[i][j] = __builtin_amdgcn_mfma_f32_16x16x32_bf16(a[i], b[j], acc[i][j], 0, 0, 0);
    }
  }

#pragma unroll
  for (int i = 0; i < 4; ++i) {
#pragma unroll
    for (int j = 0; j < 2; ++j) {
#pragma unroll
      for (int r = 0; r < 4; ++r) {
        int gm = tileM + m0 + i * 16 + kq * 4 + r;   // C/D: row = quad*4 + reg
        int gn = tileN + n0 + j * 16 + l15;          //      col = lane&15
        size_t idx = (size_t)gm * D_ + gn;
        float val = acc[i][j][r] + bias[gn];
        if (EPI == 0) {
          outF[idx] = val;
        } else if (EPI == 1) {
          outB[idx] = f2bf(val);
        } else if (EPI == 2) {
          outF[idx] = val; outB[idx] = f2bf(val);
        } else {
          float sg = 1.f / (1.f + __expf(-val));
          outF[idx] = aux[idx] * sg;
        }
      }
    }
  }
}

// ---------------- fused RMSNorm (full D) + RoPE, fp32 in -> bf16 out (x oscale) ----------------
__global__ void k_normrope(const float* __restrict__ in, const float* __restrict__ g,
                           const float* __restrict__ cs, const float* __restrict__ sn,
                           ushort_t* __restrict__ out, float oscale) {
  const int row = blockIdx.x;            // 0..4095 = b*T + t
  const int t = row & (T_ - 1);
  const float* x = in + (size_t)row * D_;
  const int tid = threadIdx.x;
  float ss = 0.f;
#pragma unroll
  for (int i = tid; i < 512; i += 256) {
    float4 v = ((const float4*)x)[i];
    ss += v.x * v.x + v.y * v.y + v.z * v.z + v.w * v.w;
  }
#pragma unroll
  for (int off = 1; off < 64; off <<= 1) ss += __shfl_xor(ss, off, 64);
  __shared__ float part[4];
  if ((tid & 63) == 0) part[tid >> 6] = ss;
  __syncthreads();
  float rstd = rsqrtf((part[0] + part[1] + part[2] + part[3]) * (1.f / (float)D_) + 1e-6f);
  rstd *= oscale;                        // fold attention scale*log2e into Q
#pragma unroll
  for (int p = tid; p < 1024; p += 256) {
    int head = p >> 6, i = p & 63;
    int e1 = head * HD_ + i, e2 = e1 + 64;
    float x1 = x[e1] * rstd * g[e1];
    float x2 = x[e2] * rstd * g[e2];
    float c = cs[t * 64 + i], s = sn[t * 64 + i];
    out[(size_t)row * D_ + e1] = f2bf(x1 * c - s * x2);
    out[(size_t)row * D_ + e2] = f2bf(x2 * c + s * x1);
  }
}

// ---------------- V transpose per head: v[b][t][h*128+d] -> vt[bh][d][t] ----------------
__global__ void k_tv(const ushort_t* __restrict__ v, ushort_t* __restrict__ vt) {
  __shared__ ushort_t tile[32][33];
  int bh = blockIdx.z, b = bh >> 4, h = bh & 15;
  int tx = threadIdx.x, ty = threadIdx.y;
  int d = blockIdx.x * 32 + tx;
  int t0 = blockIdx.y * 32;
#pragma unroll
  for (int k = 0; k < 4; ++k)
    tile[ty + k * 8][tx] = v[(size_t)(b * T_ + t0 + ty + k * 8) * D_ + h * HD_ + d];
  __syncthreads();
  int ot = t0 + tx;
  int od0 = blockIdx.x * 32;
#pragma unroll
  for (int k = 0; k < 4; ++k)
    vt[((size_t)bh * HD_ + od0 + ty + k * 8) * T_ + ot] = tile[tx][ty + k * 8];
}

// ---------------- flash v9: 32x32x16 MFMAs -- halves LDS operand bytes per FLOP
// (32 FLOP/elem vs 16), +15% MFMA ceiling. QBLK=128 (4 waves x 32 q), KVBLK=32.
// Swapped QK (A=K, B=Q): lane owns q=lane&31, 16 keys across regs; denominator
// lane-local (one shfl_xor(32) at end). P via LDS with 72B-padded rows (18-word
// stride -> only q/q+16 alias = 2/bank minimum = free; fixes R6's 2.1M conflicts).
// K/V dbuf + single vmcnt(0)+barrier per iter + setprio + XCD swizzle carried over.
__global__ __launch_bounds__(256) void k_flash(
    const ushort_t* __restrict__ Q, const ushort_t* __restrict__ K,
    const ushort_t* __restrict__ Vt, ushort_t* __restrict__ O) {
  __shared__ __align__(16) short Ks[2][32 * 128];   // [buf][key][d]   8 KB each
  __shared__ __align__(16) short Vs[2][128 * 32];   // [buf][d][key]   8 KB each
  __shared__ __align__(16) short Ps[4][32 * 36];    // per-wave P[q][key], 72B rows

  const int tid = threadIdx.x;
  const int wv = tid >> 6, lane = tid & 63;
  const int l31 = lane & 31, hi = lane >> 5;
  const int flat = blockIdx.x;                       // 512 blocks
  const int swz = (flat & 7) * 64 + (flat >> 3);     // bijective XCD chunking (512=8*64)
  const int bh = swz >> 4, b = bh >> 4, h = bh & 15;
  const int q0 = (swz & 15) * 128;

  const ushort_t* kp[2];
  const ushort_t* vp[2];
#pragma unroll
  for (int rr = 0; rr < 2; ++rr) {
    int c = rr * 256 + tid;
    int krow = c >> 4, kc = (c & 15) ^ (krow & 15);       // 16 chunks/row (128 d)
    kp[rr] = K + (size_t)(b * T_ + krow) * D_ + h * HD_ + kc * 8;
    int drow = c >> 2, vc = (c & 3) ^ ((drow >> 1) & 3);  // 4 chunks/row (32 keys)
    vp[rr] = Vt + ((size_t)bh * HD_ + drow) * T_ + vc * 8;
  }

  // Q B-frags in registers: wave owns 32 q-rows (q0 + wv*32 + l31); scale pre-folded.
  // 32x32x16 A/B layout: row/col = lane&31, k = 8*(lane>>5) + e.
  bf16x8 qa[8];
  {
    const ushort_t* qp = Q + (size_t)(b * T_ + q0 + wv * 32 + l31) * D_ + h * HD_ + hi * 8;
#pragma unroll
    for (int kk = 0; kk < 8; ++kk) qa[kk] = *(const bf16x8*)(qp + kk * 16);
  }

  // P LDS addressing (72B rows): write b64 at q*72 + (2g+hi)*8; read b64 pair at
  // q*72 + 32c + 16hi (+0,+8) = keys 16c+8hi..+7 of row q.
  char* const psb = (char*)&Ps[wv][0];
  char* const psw = psb + l31 * 72 + hi * 8;
  const char* const psr = psb + l31 * 72 + hi * 16;

  f32x16 o[4];
#pragma unroll
  for (int dt = 0; dt < 4; ++dt)
#pragma unroll
    for (int e = 0; e < 16; ++e) o[dt][e] = 0.f;
  float lsum = 0.f;                      // partial denominator for q=l31 (16 of 32 keys)

  // prologue: stage K(0), V(0) into buf 0
#pragma unroll
  for (int rr = 0; rr < 2; ++rr)
    async16(kp[rr], &Ks[0][(rr * 256 + wv * 64) * 8]);
#pragma unroll
  for (int rr = 0; rr < 2; ++rr)
    async16(vp[rr], &Vs[0][(rr * 256 + wv * 64) * 8]);

  for (int kt = 0; kt < 64; ++kt) {
    const int buf = kt & 1;
    // my stages of [buf] done; barrier -> everyone's done (and [buf^1] free to overwrite)
    __asm__ volatile("s_waitcnt vmcnt(0)" ::: "memory");
    __builtin_amdgcn_s_barrier();

    if (kt + 1 < 64) {
#pragma unroll
      for (int rr = 0; rr < 2; ++rr)
        async16(kp[rr] + (size_t)(kt + 1) * 32 * D_, &Ks[buf ^ 1][(rr * 256 + wv * 64) * 8]);
#pragma unroll
      for (int rr = 0; rr < 2; ++rr)
        async16(vp[rr] + (size_t)(kt + 1) * 32, &Vs[buf ^ 1][(rr * 256 + wv * 64) * 8]);
    }

    // S^T = K*Q^T (A=K rows=keys, B=Q cols=q): D col = q = l31 (lane-local),
    // row = key = (r&3) + 8*(r>>2) + 4*hi over regs r=0..15.
    f32x16 s;
#pragma unroll
    for (int e = 0; e < 16; ++e) s[e] = 0.f;
    __builtin_amdgcn_s_setprio(1);
#pragma unroll
    for (int kk = 0; kk < 8; ++kk) {
      bf16x8 kf = *(const bf16x8*)&Ks[buf][l31 * 128 + (((kk << 1) + hi) ^ (l31 & 15)) * 8];
      s = __builtin_amdgcn_mfma_f32_32x32x16_bf16(kf, qa[kk], s, 0, 0, 0);
    }
    __builtin_amdgcn_s_setprio(0);

    // fixed-max softmax (exp2 domain): lane-local partials; pack 4 consecutive keys
    // (regs 4g..4g+3 = keys 8g+4hi..+3) -> one b64 store each.
#pragma unroll
    for (int g = 0; g < 4; ++g) {
      float p0 = __builtin_amdgcn_exp2f(s[4 * g + 0]);
      float p1 = __builtin_amdgcn_exp2f(s[4 * g + 1]);
      float p2 = __builtin_amdgcn_exp2f(s[4 * g + 2]);
      float p3 = __builtin_amdgcn_exp2f(s[4 * g + 3]);
      lsum += (p0 + p1) + (p2 + p3);
      u32x2 w;
      w.x = cvtpk(p0, p1);
      w.y = cvtpk(p2, p3);
      *(u32x2*)(psw + g * 16) = w;
    }
    __asm__ volatile("s_waitcnt lgkmcnt(0)" ::: "memory");   // P writes -> cross-lane reads

    // P A-frags: row q = l31, kchunk c: keys 16c+8hi..+7
    bf16x8 pf[2];
#pragma unroll
    for (int c = 0; c < 2; ++c) {
      u32x2 a = *(const u32x2*)(psr + c * 32);
      u32x2 bq = *(const u32x2*)(psr + c * 32 + 8);
      pf[c] = mk8(a.x, a.y, bq.x, bq.y);
    }

    // O += P * V: B=V col = d = l31, k = key chunk; D col = d = l31, row = q
    __builtin_amdgcn_s_setprio(1);
#pragma unroll
    for (int dt = 0; dt < 4; ++dt) {
      int vrow = dt * 32 + l31;
#pragma unroll
      for (int c = 0; c < 2; ++c) {
        bf16x8 vf = *(const bf16x8*)&Vs[buf][vrow * 32 + (((c << 1) + hi) ^ ((vrow >> 1) & 3)) * 8];
        o[dt] = __builtin_amdgcn_mfma_f32_32x32x16_bf16(pf[c], vf, o[dt], 0, 0, 0);
      }
    }
    __builtin_amdgcn_s_setprio(0);
  }

  // full denominator: lane covers 16 keys, partner lane^32 the other 16
  lsum += __shfl_xor(lsum, 32, 64);

  // store: o[dt][r] is O[q = (r&3)+8*(r>>2)+4*hi][d = dt*32 + l31]
#pragma unroll
  for (int r = 0; r < 16; ++r) {
    int qrow = (r & 3) + 8 * (r >> 2) + 4 * hi;
    float inv = 1.f / __shfl(lsum, qrow, 64);
    size_t row = (size_t)(b * T_ + q0 + wv * 32 + qrow);
#pragma unroll
    for (int dt = 0; dt < 4; ++dt)
      O[row * D_ + h * HD_ + dt * 32 + l31] = f2bf(o[dt][r] * inv);
  }
}

// ---------------- launch ----------------
extern "C" void kernel_launch(void* const* d_in, const int* in_sizes, int n_in,
                              void* d_out, int out_size, void* d_ws, size_t ws_size,
                              hipStream_t stream) {
  const float* x  = (const float*)d_in[0];
  const float* cs = (const float*)d_in[1];
  const float* sn = (const float*)d_in[2];
  const float* wq = (const float*)d_in[3];
  const float* bq = (const float*)d_in[4];
  const float* wk = (const float*)d_in[5];
  const float* bk = (const float*)d_in[6];
  const float* wv = (const float*)d_in[7];
  const float* bv = (const float*)d_in[8];
  const float* gq = (const float*)d_in[9];
  const float* gk = (const float*)d_in[10];
  const float* wo = (const float*)d_in[11];
  const float* bo = (const float*)d_in[12];
  const float* wg = (const float*)d_in[13];
  const float* bg = (const float*)d_in[14];

  char* ws = (char*)d_ws;
  const size_t SZ_BTD_BF = (size_t)BT_ * D_ * 2;   // 16 MB
  const size_t SZ_DD_BF  = (size_t)D_ * D_ * 2;    //  8 MB
  const size_t SZ_BTD_F  = (size_t)BT_ * D_ * 4;   // 32 MB

  size_t off = 0;
  ushort_t* xb  = (ushort_t*)(ws + off); off += SZ_BTD_BF;        // aliased as attn later
  ushort_t* wqT = (ushort_t*)(ws + off); off += SZ_DD_BF;
  ushort_t* wkT = (ushort_t*)(ws + off); off += SZ_DD_BF;
  ushort_t* wvT = (ushort_t*)(ws + off); off += SZ_DD_BF;
  ushort_t* woT = (ushort_t*)(ws + off); off += SZ_DD_BF;
  ushort_t* wgT = (ushort_t*)(ws + off); off += SZ_DD_BF;
  float*    qf  = (float*)(ws + off);    off += SZ_BTD_F;         // aliased as outf later
  float*    kf  = (float*)(ws + off);    off += SZ_BTD_F;         // aliased as outb later
  ushort_t* vb  = (ushort_t*)(ws + off); off += SZ_BTD_BF;
  ushort_t* qb  = (ushort_t*)(ws + off); off += SZ_BTD_BF;
  ushort_t* kb  = (ushort_t*)(ws + off); off += SZ_BTD_BF;
  ushort_t* vt  = (ushort_t*)(ws + off); off += SZ_BTD_BF;        // ~193 MB total
  ushort_t* attn = xb;            // xb dead after QKV GEMMs
  float*    outf = qf;            // qf dead after norm_rope(q)
  ushort_t* outb = (ushort_t*)kf; // kf dead after norm_rope(k)

  const float cl2 = 0.08838834764831845f * 1.4426950408889634f;  // 1/sqrt(128)*log2e

  k_cast_x<<<8192, 256, 0, stream>>>(x, xb);
  k_twT5<<<dim3(64, 64, 5), dim3(32, 8), 0, stream>>>(wq, wk, wv, wo, wg,
                                                      wqT, wkT, wvT, woT, wgT);

  k_gemm<0><<<dim3(16, 32), 512, 0, stream>>>(xb, wqT, bq, qf, nullptr, nullptr);
  k_gemm<0><<<dim3(16, 32), 512, 0, stream>>>(xb, wkT, bk, kf, nullptr, nullptr);
  k_gemm<1><<<dim3(16, 32), 512, 0, stream>>>(xb, wvT, bv, nullptr, vb, nullptr);

  k_normrope<<<4096, 256, 0, stream>>>(qf, gq, cs, sn, qb, cl2);
  k_normrope<<<4096, 256, 0, stream>>>(kf, gk, cs, sn, kb, 1.0f);
  k_tv<<<dim3(4, 64, 32), dim3(32, 8), 0, stream>>>(vb, vt);

  k_flash<<<512, 256, 0, stream>>>(qb, kb, vt, attn);

  k_gemm<2><<<dim3(16, 32), 512, 0, stream>>>(attn, woT, bo, outf, outb, nullptr);
  k_gemm<3><<<dim3(16, 32), 512, 0, stream>>>(outb, wgT, bg, (float*)d_out, nullptr, outf);
}

// Round 8
// 495.257 us; speedup vs baseline: 1.2225x; 1.0107x over previous
//
#include <hip/hip_runtime.h>
#include <stdint.h>

typedef unsigned short ushort_t;
typedef __attribute__((ext_vector_type(8))) short bf16x8;
typedef __attribute__((ext_vector_type(4))) float f32x4;
typedef __attribute__((ext_vector_type(16))) float f32x16;
typedef __attribute__((ext_vector_type(4))) unsigned short u16x4;

#define B_ 2
#define T_ 2048
#define D_ 2048
#define H_ 16
#define HD_ 128
#define BT_ 4096

__device__ __forceinline__ ushort_t f2bf(float f) {
  unsigned u = __float_as_uint(f);
  u += 0x7FFFu + ((u >> 16) & 1u);   // RNE
  return (ushort_t)(u >> 16);
}

// pack two f32 -> u32 of 2 bf16 (RNE), low = first arg [T12 primitive, m214v22]
__device__ __forceinline__ unsigned cvtpk(float lo, float hi) {
  unsigned r;
  asm("v_cvt_pk_bf16_f32 %0, %1, %2" : "=v"(r) : "v"(lo), "v"(hi));
  return r;
}

__device__ __forceinline__ bf16x8 mk8(unsigned a, unsigned b, unsigned c, unsigned d) {
  union { unsigned u[4]; bf16x8 v; } x;
  x.u[0] = a; x.u[1] = b; x.u[2] = c; x.u[3] = d;
  return x.v;
}

__device__ __forceinline__ void async16(const void* g, void* l) {
  __builtin_amdgcn_global_load_lds(
      (const __attribute__((address_space(1))) unsigned int*)g,
      (__attribute__((address_space(3))) unsigned int*)l, 16, 0, 0);
}

// ---------------- elementwise cast x -> bf16 ----------------
__global__ void k_cast_x(const float* __restrict__ in, ushort_t* __restrict__ out) {
  int i = blockIdx.x * 256 + threadIdx.x;          // 4 elements per thread
  float4 v = ((const float4*)in)[i];
  u16x4 r = { f2bf(v.x), f2bf(v.y), f2bf(v.z), f2bf(v.w) };
  ((u16x4*)out)[i] = r;
}

// ---------------- fused weight transpose+cast x5: w[K][N] f32 -> wt[N][K] bf16 ----------------
__global__ void k_twT5(const float* __restrict__ wa, const float* __restrict__ wb,
                       const float* __restrict__ wc, const float* __restrict__ wd,
                       const float* __restrict__ we,
                       ushort_t* __restrict__ ta, ushort_t* __restrict__ tb,
                       ushort_t* __restrict__ tc, ushort_t* __restrict__ td,
                       ushort_t* __restrict__ te) {
  const float* w; ushort_t* wt;
  switch (blockIdx.z) {
    case 0: w = wa; wt = ta; break;
    case 1: w = wb; wt = tb; break;
    case 2: w = wc; wt = tc; break;
    case 3: w = wd; wt = td; break;
    default: w = we; wt = te; break;
  }
  __shared__ float tile[32][33];
  int tx = threadIdx.x, ty = threadIdx.y;
  int x = blockIdx.x * 32 + tx;        // N index
  int y0 = blockIdx.y * 32;            // K index
#pragma unroll
  for (int k = 0; k < 4; ++k)
    tile[ty + k * 8][tx] = w[(size_t)(y0 + ty + k * 8) * D_ + x];
  __syncthreads();
  int ox = blockIdx.y * 32 + tx;       // K contiguous on write
  int oy0 = blockIdx.x * 32;           // N
#pragma unroll
  for (int k = 0; k < 4; ++k)
    wt[(size_t)(oy0 + ty + k * 8) * D_ + ox] = f2bf(tile[tx][ty + k * 8]);
}

// ---------------- GEMM: C[M=4096][N=2048] = A(bf16 MxK) * Bt(bf16 NxK)^T + bias ----------------
// 512 threads / 8 waves (each 64x32), 128x128 tile, BK=64, dbuf, one barrier per K-step.
// EPI 0: fp32. 1: bf16. 2: both. 3: gate (out = aux*sigmoid(val))
template <int EPI>
__global__ __launch_bounds__(512) void k_gemm(
    const ushort_t* __restrict__ A, const ushort_t* __restrict__ Bt,
    const float* __restrict__ bias, float* __restrict__ outF,
    ushort_t* __restrict__ outB, const float* __restrict__ aux) {
  __shared__ __align__(16) short As[2][128 * 64];
  __shared__ __align__(16) short Bs[2][128 * 64];
  const int tid = threadIdx.x;
  const int wid = tid >> 6, lane = tid & 63;
  const int l15 = lane & 15, kq = lane >> 4;
  const int m0 = (wid >> 2) * 64, n0 = (wid & 3) * 32;
  const int tileM = blockIdx.y * 128, tileN = blockIdx.x * 128;

  f32x4 acc[4][2];
#pragma unroll
  for (int i = 0; i < 4; ++i)
#pragma unroll
    for (int j = 0; j < 2; ++j) acc[i][j] = (f32x4){0.f, 0.f, 0.f, 0.f};

  auto stage = [&](int sbuf, int k0) {
#pragma unroll
    for (int rr = 0; rr < 2; ++rr) {
      int c = rr * 512 + tid;          // 1024 chunks of 16B per matrix
      int row = c >> 3, p = c & 7;
      int gc = p ^ (row & 7);          // XOR-swizzled global chunk (bank-conflict fix)
      async16(A + (size_t)(tileM + row) * D_ + k0 + gc * 8,
              &As[sbuf][(rr * 512 + wid * 64) * 8]);
      async16(Bt + (size_t)(tileN + row) * D_ + k0 + gc * 8,
              &Bs[sbuf][(rr * 512 + wid * 64) * 8]);
    }
  };

  stage(0, 0);
  for (int k0 = 0; k0 < D_; k0 += 64) {
    const int buf = (k0 >> 6) & 1;
    __asm__ volatile("s_waitcnt vmcnt(0)" ::: "memory");
    __builtin_amdgcn_s_barrier();
    if (k0 + 64 < D_) stage(buf ^ 1, k0 + 64);   // lands during compute below
#pragma unroll
    for (int half = 0; half < 2; ++half) {
      bf16x8 a[4], b[2];
#pragma unroll
      for (int i = 0; i < 4; ++i) {
        int row = m0 + i * 16 + l15;
        a[i] = *(const bf16x8*)&As[buf][row * 64 + ((half * 4 + kq) ^ (row & 7)) * 8];
      }
#pragma unroll
      for (int j = 0; j < 2; ++j) {
        int row = n0 + j * 16 + l15;
        b[j] = *(const bf16x8*)&Bs[buf][row * 64 + ((half * 4 + kq) ^ (row & 7)) * 8];
      }
#pragma unroll
      for (int i = 0; i < 4; ++i)
#pragma unroll
        for (int j = 0; j < 2; ++j)
          acc[i][j] = __builtin_amdgcn_mfma_f32_16x16x32_bf16(a[i], b[j], acc[i][j], 0, 0, 0);
    }
  }

#pragma unroll
  for (int i = 0; i < 4; ++i) {
#pragma unroll
    for (int j = 0; j < 2; ++j) {
#pragma unroll
      for (int r = 0; r < 4; ++r) {
        int gm = tileM + m0 + i * 16 + kq * 4 + r;   // C/D: row = quad*4 + reg
        int gn = tileN + n0 + j * 16 + l15;          //      col = lane&15
        size_t idx = (size_t)gm * D_ + gn;
        float val = acc[i][j][r] + bias[gn];
        if (EPI == 0) {
          outF[idx] = val;
        } else if (EPI == 1) {
          outB[idx] = f2bf(val);
        } else if (EPI == 2) {
          outF[idx] = val; outB[idx] = f2bf(val);
        } else {
          float sg = 1.f / (1.f + __expf(-val));
          outF[idx] = aux[idx] * sg;
        }
      }
    }
  }
}

// ---------------- fused RMSNorm (full D) + RoPE, fp32 in -> bf16 out (x oscale) ----------------
__global__ void k_normrope(const float* __restrict__ in, const float* __restrict__ g,
                           const float* __restrict__ cs, const float* __restrict__ sn,
                           ushort_t* __restrict__ out, float oscale) {
  const int row = blockIdx.x;            // 0..4095 = b*T + t
  const int t = row & (T_ - 1);
  const float* x = in + (size_t)row * D_;
  const int tid = threadIdx.x;
  float ss = 0.f;
#pragma unroll
  for (int i = tid; i < 512; i += 256) {
    float4 v = ((const float4*)x)[i];
    ss += v.x * v.x + v.y * v.y + v.z * v.z + v.w * v.w;
  }
#pragma unroll
  for (int off = 1; off < 64; off <<= 1) ss += __shfl_xor(ss, off, 64);
  __shared__ float part[4];
  if ((tid & 63) == 0) part[tid >> 6] = ss;
  __syncthreads();
  float rstd = rsqrtf((part[0] + part[1] + part[2] + part[3]) * (1.f / (float)D_) + 1e-6f);
  rstd *= oscale;                        // fold attention scale*log2e into Q
#pragma unroll
  for (int p = tid; p < 1024; p += 256) {
    int head = p >> 6, i = p & 63;
    int e1 = head * HD_ + i, e2 = e1 + 64;
    float x1 = x[e1] * rstd * g[e1];
    float x2 = x[e2] * rstd * g[e2];
    float c = cs[t * 64 + i], s = sn[t * 64 + i];
    out[(size_t)row * D_ + e1] = f2bf(x1 * c - s * x2);
    out[(size_t)row * D_ + e2] = f2bf(x2 * c + s * x1);
  }
}

// ---------------- V transpose per head: v[b][t][h*128+d] -> vt[bh][d][t] ----------------
__global__ void k_tv(const ushort_t* __restrict__ v, ushort_t* __restrict__ vt) {
  __shared__ ushort_t tile[32][33];
  int bh = blockIdx.z, b = bh >> 4, h = bh & 15;
  int tx = threadIdx.x, ty = threadIdx.y;
  int d = blockIdx.x * 32 + tx;
  int t0 = blockIdx.y * 32;
#pragma unroll
  for (int k = 0; k < 4; ++k)
    tile[ty + k * 8][tx] = v[(size_t)(b * T_ + t0 + ty + k * 8) * D_ + h * HD_ + d];
  __syncthreads();
  int ot = t0 + tx;
  int od0 = blockIdx.x * 32;
#pragma unroll
  for (int k = 0; k < 4; ++k)
    vt[((size_t)bh * HD_ + od0 + ty + k * 8) * T_ + ot] = tile[tx][ty + k * 8];
}

// ---------------- flash v10: 32x32x16, P transpose fully IN-REGISTER (T12).
// Swapped QK: s[r'] at lane (l31,hi') = P^T[key=(r'&3)+8(r'>>2)+4hi'][q=l31].
// PV A-frag elem e of pf[c] = P[q=l31][key=16c+8hi+e] -> source reg (e&3)+4(2c+hi)
// at lane l31+32*((e>>2)&1): SAME l31, pure lo/hi half-wave exchange = permlane32_swap.
// Packing w[j]=cvtpk(p[2j],p[2j+1]): swap(w0,w2)->(pf0.w0,pf0.w2), swap(w1,w3)->
// (pf0.w1,pf0.w3), swap(w4,w6)/swap(w5,w7)->pf1. Removes Ps LDS (42->33KB), all P
// ds-ops, the lgkmcnt(0) drain, and R7's 4.19M bank conflicts. QK accumulator split
// into 2 chains (sA/sB) to halve MFMA dep depth. K/V dbuf + 1 barrier/iter kept.
__global__ __launch_bounds__(256) void k_flash(
    const ushort_t* __restrict__ Q, const ushort_t* __restrict__ K,
    const ushort_t* __restrict__ Vt, ushort_t* __restrict__ O) {
  __shared__ __align__(16) short Ks[2][32 * 128];   // [buf][key][d]   8 KB each
  __shared__ __align__(16) short Vs[2][128 * 32];   // [buf][d][key]   8 KB each

  const int tid = threadIdx.x;
  const int wv = tid >> 6, lane = tid & 63;
  const int l31 = lane & 31, hi = lane >> 5;
  const int flat = blockIdx.x;                       // 512 blocks
  const int swz = (flat & 7) * 64 + (flat >> 3);     // bijective XCD chunking (512=8*64)
  const int bh = swz >> 4, b = bh >> 4, h = bh & 15;
  const int q0 = (swz & 15) * 128;

  const ushort_t* kp[2];
  const ushort_t* vp[2];
#pragma unroll
  for (int rr = 0; rr < 2; ++rr) {
    int c = rr * 256 + tid;
    int krow = c >> 4, kc = (c & 15) ^ (krow & 15);       // 16 chunks/row (128 d)
    kp[rr] = K + (size_t)(b * T_ + krow) * D_ + h * HD_ + kc * 8;
    int drow = c >> 2, vc = (c & 3) ^ ((drow >> 1) & 3);  // 4 chunks/row (32 keys)
    vp[rr] = Vt + ((size_t)bh * HD_ + drow) * T_ + vc * 8;
  }

  // Q B-frags in registers: wave owns 32 q-rows (q0 + wv*32 + l31); scale pre-folded.
  // 32x32x16 A/B layout: row/col = lane&31, k = 8*(lane>>5) + e.
  bf16x8 qa[8];
  {
    const ushort_t* qp = Q + (size_t)(b * T_ + q0 + wv * 32 + l31) * D_ + h * HD_ + hi * 8;
#pragma unroll
    for (int kk = 0; kk < 8; ++kk) qa[kk] = *(const bf16x8*)(qp + kk * 16);
  }

  f32x16 o[4];
#pragma unroll
  for (int dt = 0; dt < 4; ++dt)
#pragma unroll
    for (int e = 0; e < 16; ++e) o[dt][e] = 0.f;
  float lsum = 0.f;                      // partial denominator for q=l31 (16 of 32 keys)

  // prologue: stage K(0), V(0) into buf 0
#pragma unroll
  for (int rr = 0; rr < 2; ++rr)
    async16(kp[rr], &Ks[0][(rr * 256 + wv * 64) * 8]);
#pragma unroll
  for (int rr = 0; rr < 2; ++rr)
    async16(vp[rr], &Vs[0][(rr * 256 + wv * 64) * 8]);

  for (int kt = 0; kt < 64; ++kt) {
    const int buf = kt & 1;
    // my stages of [buf] done; barrier -> everyone's done (and [buf^1] free to overwrite)
    __asm__ volatile("s_waitcnt vmcnt(0)" ::: "memory");
    __builtin_amdgcn_s_barrier();

    if (kt + 1 < 64) {
#pragma unroll
      for (int rr = 0; rr < 2; ++rr)
        async16(kp[rr] + (size_t)(kt + 1) * 32 * D_, &Ks[buf ^ 1][(rr * 256 + wv * 64) * 8]);
#pragma unroll
      for (int rr = 0; rr < 2; ++rr)
        async16(vp[rr] + (size_t)(kt + 1) * 32, &Vs[buf ^ 1][(rr * 256 + wv * 64) * 8]);
    }

    // S^T = K*Q^T (A=K rows=keys, B=Q cols=q): two accumulator chains (dep depth 4)
    f32x16 sA, sB;
#pragma unroll
    for (int e = 0; e < 16; ++e) { sA[e] = 0.f; sB[e] = 0.f; }
    __builtin_amdgcn_s_setprio(1);
#pragma unroll
    for (int m = 0; m < 4; ++m) {
      bf16x8 kf0 = *(const bf16x8*)&Ks[buf][l31 * 128 + (((4 * m) + hi) ^ (l31 & 15)) * 8];
      sA = __builtin_amdgcn_mfma_f32_32x32x16_bf16(kf0, qa[2 * m], sA, 0, 0, 0);
      bf16x8 kf1 = *(const bf16x8*)&Ks[buf][l31 * 128 + (((4 * m + 2) + hi) ^ (l31 & 15)) * 8];
      sB = __builtin_amdgcn_mfma_f32_32x32x16_bf16(kf1, qa[2 * m + 1], sB, 0, 0, 0);
    }
    __builtin_amdgcn_s_setprio(0);

    // fixed-max softmax (exp2 domain): lane-local partials, pack to bf16 words
    unsigned w[8];
#pragma unroll
    for (int j = 0; j < 8; ++j) {
      float pa = __builtin_amdgcn_exp2f(sA[2 * j] + sB[2 * j]);
      float pb = __builtin_amdgcn_exp2f(sA[2 * j + 1] + sB[2 * j + 1]);
      lsum += pa + pb;
      w[j] = cvtpk(pa, pb);
    }

    // in-register P transpose: lo/hi half-wave exchange (vdst[32:63] <-> vsrc[0:31])
    auto r02 = __builtin_amdgcn_permlane32_swap(w[0], w[2], false, false);
    auto r13 = __builtin_amdgcn_permlane32_swap(w[1], w[3], false, false);
    auto r46 = __builtin_amdgcn_permlane32_swap(w[4], w[6], false, false);
    auto r57 = __builtin_amdgcn_permlane32_swap(w[5], w[7], false, false);
    bf16x8 pf0 = mk8(r02[0], r13[0], r02[1], r13[1]);
    bf16x8 pf1 = mk8(r46[0], r57[0], r46[1], r57[1]);

    // O += P * V: B=V col = d = l31, k = key chunk; D col = d = l31, row = q
    __builtin_amdgcn_s_setprio(1);
#pragma unroll
    for (int dt = 0; dt < 4; ++dt) {
      int vrow = dt * 32 + l31;
      bf16x8 vf0 = *(const bf16x8*)&Vs[buf][vrow * 32 + ((hi) ^ ((vrow >> 1) & 3)) * 8];
      o[dt] = __builtin_amdgcn_mfma_f32_32x32x16_bf16(pf0, vf0, o[dt], 0, 0, 0);
      bf16x8 vf1 = *(const bf16x8*)&Vs[buf][vrow * 32 + ((2 + hi) ^ ((vrow >> 1) & 3)) * 8];
      o[dt] = __builtin_amdgcn_mfma_f32_32x32x16_bf16(pf1, vf1, o[dt], 0, 0, 0);
    }
    __builtin_amdgcn_s_setprio(0);
  }

  // full denominator: lane covers 16 keys, partner lane^32 the other 16
  lsum += __shfl_xor(lsum, 32, 64);

  // store: o[dt][r] is O[q = (r&3)+8*(r>>2)+4*hi][d = dt*32 + l31]
#pragma unroll
  for (int r = 0; r < 16; ++r) {
    int qrow = (r & 3) + 8 * (r >> 2) + 4 * hi;
    float inv = 1.f / __shfl(lsum, qrow, 64);
    size_t row = (size_t)(b * T_ + q0 + wv * 32 + qrow);
#pragma unroll
    for (int dt = 0; dt < 4; ++dt)
      O[row * D_ + h * HD_ + dt * 32 + l31] = f2bf(o[dt][r] * inv);
  }
}

// ---------------- launch ----------------
extern "C" void kernel_launch(void* const* d_in, const int* in_sizes, int n_in,
                              void* d_out, int out_size, void* d_ws, size_t ws_size,
                              hipStream_t stream) {
  const float* x  = (const float*)d_in[0];
  const float* cs = (const float*)d_in[1];
  const float* sn = (const float*)d_in[2];
  const float* wq = (const float*)d_in[3];
  const float* bq = (const float*)d_in[4];
  const float* wk = (const float*)d_in[5];
  const float* bk = (const float*)d_in[6];
  const float* wv = (const float*)d_in[7];
  const float* bv = (const float*)d_in[8];
  const float* gq = (const float*)d_in[9];
  const float* gk = (const float*)d_in[10];
  const float* wo = (const float*)d_in[11];
  const float* bo = (const float*)d_in[12];
  const float* wg = (const float*)d_in[13];
  const float* bg = (const float*)d_in[14];

  char* ws = (char*)d_ws;
  const size_t SZ_BTD_BF = (size_t)BT_ * D_ * 2;   // 16 MB
  const size_t SZ_DD_BF  = (size_t)D_ * D_ * 2;    //  8 MB
  const size_t SZ_BTD_F  = (size_t)BT_ * D_ * 4;   // 32 MB

  size_t off = 0;
  ushort_t* xb  = (ushort_t*)(ws + off); off += SZ_BTD_BF;        // aliased as attn later
  ushort_t* wqT = (ushort_t*)(ws + off); off += SZ_DD_BF;
  ushort_t* wkT = (ushort_t*)(ws + off); off += SZ_DD_BF;
  ushort_t* wvT = (ushort_t*)(ws + off); off += SZ_DD_BF;
  ushort_t* woT = (ushort_t*)(ws + off); off += SZ_DD_BF;
  ushort_t* wgT = (ushort_t*)(ws + off); off += SZ_DD_BF;
  float*    qf  = (float*)(ws + off);    off += SZ_BTD_F;         // aliased as outf later
  float*    kf  = (float*)(ws + off);    off += SZ_BTD_F;         // aliased as outb later
  ushort_t* vb  = (ushort_t*)(ws + off); off += SZ_BTD_BF;
  ushort_t* qb  = (ushort_t*)(ws + off); off += SZ_BTD_BF;
  ushort_t* kb  = (ushort_t*)(ws + off); off += SZ_BTD_BF;
  ushort_t* vt  = (ushort_t*)(ws + off); off += SZ_BTD_BF;        // ~193 MB total
  ushort_t* attn = xb;            // xb dead after QKV GEMMs
  float*    outf = qf;            // qf dead after norm_rope(q)
  ushort_t* outb = (ushort_t*)kf; // kf dead after norm_rope(k)

  const float cl2 = 0.08838834764831845f * 1.4426950408889634f;  // 1/sqrt(128)*log2e

  k_cast_x<<<8192, 256, 0, stream>>>(x, xb);
  k_twT5<<<dim3(64, 64, 5), dim3(32, 8), 0, stream>>>(wq, wk, wv, wo, wg,
                                                      wqT, wkT, wvT, woT, wgT);

  k_gemm<0><<<dim3(16, 32), 512, 0, stream>>>(xb, wqT, bq, qf, nullptr, nullptr);
  k_gemm<0><<<dim3(16, 32), 512, 0, stream>>>(xb, wkT, bk, kf, nullptr, nullptr);
  k_gemm<1><<<dim3(16, 32), 512, 0, stream>>>(xb, wvT, bv, nullptr, vb, nullptr);

  k_normrope<<<4096, 256, 0, stream>>>(qf, gq, cs, sn, qb, cl2);
  k_normrope<<<4096, 256, 0, stream>>>(kf, gk, cs, sn, kb, 1.0f);
  k_tv<<<dim3(4, 64, 32), dim3(32, 8), 0, stream>>>(vb, vt);

  k_flash<<<512, 256, 0, stream>>>(qb, kb, vt, attn);

  k_gemm<2><<<dim3(16, 32), 512, 0, stream>>>(attn, woT, bo, outf, outb, nullptr);
  k_gemm<3><<<dim3(16, 32), 512, 0, stream>>>(outb, wgT, bg, (float*)d_out, nullptr, outf);
}